// Round 1
// baseline (631.765 us; speedup 1.0000x reference)
//
#include <hip/hip_runtime.h>
#include <hip/hip_bf16.h>

#define NNODES 20000
#define NEDGES 500000
#define LRELU(v) ((v) > 0.f ? (v) : (v) * 0.01f)

// ---------------------------------------------------------------------------
// CSR build: histogram -> exclusive scan -> scatter (sorted src per dst)
// ---------------------------------------------------------------------------
__global__ __launch_bounds__(256) void k_hist(const int* __restrict__ dst,
                                              int* __restrict__ deg, int ne) {
  int i = blockIdx.x * 256 + threadIdx.x;
  if (i < ne) atomicAdd(&deg[dst[i]], 1);
}

// single-block chunked Hillis-Steele scan; deg and cursor may alias.
__global__ __launch_bounds__(1024) void k_scan(const int* deg,
                                               int* row_off, int* cursor, int n) {
  __shared__ int sdata[1024];
  __shared__ int sbase;
  int tid = threadIdx.x;
  if (tid == 0) sbase = 0;
  __syncthreads();
  for (int start = 0; start < n; start += 1024) {
    int i = start + tid;
    int v = (i < n) ? deg[i] : 0;
    sdata[tid] = v;
    __syncthreads();
    for (int off = 1; off < 1024; off <<= 1) {
      int t = (tid >= off) ? sdata[tid - off] : 0;
      __syncthreads();
      sdata[tid] += t;
      __syncthreads();
    }
    int incl = sdata[tid];
    int base = sbase;           // read before update
    if (i < n) {
      int excl = base + incl - v;
      row_off[i] = excl;
      cursor[i] = excl;
    }
    __syncthreads();
    if (tid == 1023) sbase = base + incl;
    __syncthreads();
  }
  if (tid == 0) row_off[n] = sbase;
}

__global__ __launch_bounds__(256) void k_scatter(const int* __restrict__ src,
                                                 const int* __restrict__ dst,
                                                 int* __restrict__ cursor,
                                                 int* __restrict__ srt, int ne) {
  int i = blockIdx.x * 256 + threadIdx.x;
  if (i < ne) {
    int pos = atomicAdd(&cursor[dst[i]], 1);
    srt[pos] = src[i];
  }
}

// ---------------------------------------------------------------------------
// GEMM: Y[m][o] = sum_k X[m][k] * W[o][k] + b[o]     (K fixed = 128)
// F = out width (128 or 64). fp32 vector-ALU, LDS-staged, K-chunked (BK=64).
// ---------------------------------------------------------------------------
template <int F>
__global__ __launch_bounds__(256) void k_gemm(const float* __restrict__ X,
                                              const float* __restrict__ W,
                                              const float* __restrict__ bias,
                                              float* __restrict__ Y, int nrows) {
  constexpr int CG = F / 4;        // col groups (threads across cols)
  constexpr int RG = 256 / CG;     // row groups
  constexpr int ROWS = RG * 4;     // rows per block
  __shared__ float xs[ROWS][129];  // +1 pad breaks bank aliasing
  __shared__ float wt[64][F];      // transposed W chunk: wt[k][o]

  int tid = threadIdx.x;
  int r0 = blockIdx.x * ROWS;

  // stage X rows (full K)
  for (int idx = tid; idx < ROWS * 128; idx += 256) {
    int r = idx >> 7, k = idx & 127;
    int gr = r0 + r;
    xs[r][k] = (gr < nrows) ? X[gr * 128 + k] : 0.f;
  }

  int tc = tid % CG, tr = tid / CG;
  int lr = tr * 4, lc = tc * 4;
  float acc[4][4] = {};

  for (int kc = 0; kc < 2; ++kc) {
    __syncthreads();
    // stage transposed W chunk: wt[k][o] = W[o*128 + kc*64 + k]
    for (int idx = tid; idx < 64 * F; idx += 256) {
      int k = idx / F, o = idx % F;
      wt[k][o] = W[o * 128 + kc * 64 + k];
    }
    __syncthreads();
#pragma unroll 4
    for (int k = 0; k < 64; ++k) {
      float4 b4 = *(const float4*)&wt[k][lc];
#pragma unroll
      for (int r = 0; r < 4; ++r) {
        float a = xs[lr + r][kc * 64 + k];
        acc[r][0] += a * b4.x;
        acc[r][1] += a * b4.y;
        acc[r][2] += a * b4.z;
        acc[r][3] += a * b4.w;
      }
    }
  }

  float4 bb = *(const float4*)&bias[lc];
#pragma unroll
  for (int r = 0; r < 4; ++r) {
    int gr = r0 + lr + r;
    if (gr < nrows) {
      float4 o4 = make_float4(acc[r][0] + bb.x, acc[r][1] + bb.y,
                              acc[r][2] + bb.z, acc[r][3] + bb.w);
      *(float4*)&Y[gr * F + lc] = o4;
    }
  }
}

// ---------------------------------------------------------------------------
// Row dots: al[i] = Wh[i,:] . a[0:F]   ar[i] = Wh[i,:] . a[F:2F]
// one wave per row
// ---------------------------------------------------------------------------
template <int F>
__global__ __launch_bounds__(256) void k_rowdot(const float* __restrict__ Wh,
                                                const float* __restrict__ a,
                                                float* __restrict__ al,
                                                float* __restrict__ ar, int n) {
  int wid = threadIdx.x >> 6, lane = threadIdx.x & 63;
  int i = blockIdx.x * 4 + wid;
  if (i >= n) return;
  float pl, pr;
  if (F == 128) {
    float w0 = Wh[i * 128 + lane];
    float w1 = Wh[i * 128 + 64 + lane];
    pl = w0 * a[lane] + w1 * a[64 + lane];
    pr = w0 * a[128 + lane] + w1 * a[192 + lane];
  } else {
    float w = Wh[i * 64 + lane];
    pl = w * a[lane];
    pr = w * a[64 + lane];
  }
#pragma unroll
  for (int o = 32; o > 0; o >>= 1) {
    pl += __shfl_xor(pl, o);
    pr += __shfl_xor(pr, o);
  }
  if (lane == 0) {
    al[i] = pl;
    ar[i] = pr;
  }
}

// ---------------------------------------------------------------------------
// Aggregation: per destination node, segment-softmax over incoming edges and
// weighted sum of Wh[src]. One wave per dst node. MODE: 0=write, 1=add,
// 2=add then leaky_relu.
// ---------------------------------------------------------------------------
template <int F, int MODE>
__global__ __launch_bounds__(256) void k_agg(const int* __restrict__ row_off,
                                             const int* __restrict__ srt,
                                             const float* __restrict__ al,
                                             const float* __restrict__ ar,
                                             const float* __restrict__ Wh,
                                             float* __restrict__ H, int n) {
  int wid = threadIdx.x >> 6, lane = threadIdx.x & 63;
  int d = blockIdx.x * 4 + wid;
  if (d >= n) return;
  int beg = row_off[d], end = row_off[d + 1];
  float ard = ar[d];

  // pass 1: segment max
  float mx = -3.4e38f;
  for (int j = beg + lane; j < end; j += 64) {
    float e = al[srt[j]] + ard;
    e = LRELU(e);
    mx = fmaxf(mx, e);
  }
#pragma unroll
  for (int o = 32; o > 0; o >>= 1) mx = fmaxf(mx, __shfl_xor(mx, o));

  // pass 2: denom
  float den = 0.f;
  for (int j = beg + lane; j < end; j += 64) {
    float e = al[srt[j]] + ard;
    e = LRELU(e);
    den += __expf(e - mx);
  }
#pragma unroll
  for (int o = 32; o > 0; o >>= 1) den += __shfl_xor(den, o);
  float rden = (end > beg) ? 1.f / den : 0.f;

  // pass 3: weighted feature gather
  if (F == 128) {
    float2 acc = {0.f, 0.f};
    for (int j = beg; j < end; ++j) {
      int s = srt[j];
      float e = al[s] + ard;
      e = LRELU(e);
      float w = __expf(e - mx) * rden;
      float2 v = *(const float2*)&Wh[s * 128 + lane * 2];
      acc.x += w * v.x;
      acc.y += w * v.y;
    }
    float2* hp = (float2*)&H[d * 128 + lane * 2];
    if (MODE == 0) {
      *hp = acc;
    } else {
      float2 p = *hp;
      p.x += acc.x;
      p.y += acc.y;
      if (MODE == 2) {
        p.x = LRELU(p.x);
        p.y = LRELU(p.y);
      }
      *hp = p;
    }
  } else {
    float acc = 0.f;
    for (int j = beg; j < end; ++j) {
      int s = srt[j];
      float e = al[s] + ard;
      e = LRELU(e);
      float w = __expf(e - mx) * rden;
      acc += w * Wh[s * 64 + lane];
    }
    float* hp = &H[d * 64 + lane];
    float v = (MODE == 0) ? acc : (*hp + acc);
    if (MODE == 2) v = LRELU(v);
    *hp = v;
  }
}

// ---------------------------------------------------------------------------
// launch
// ---------------------------------------------------------------------------
extern "C" void kernel_launch(void* const* d_in, const int* in_sizes, int n_in,
                              void* d_out, int out_size, void* d_ws,
                              size_t ws_size, hipStream_t stream) {
  const float* x    = (const float*)d_in[0];
  const float* W1_0 = (const float*)d_in[1];
  const float* b1_0 = (const float*)d_in[2];
  const float* a1_0 = (const float*)d_in[3];
  const float* W1_1 = (const float*)d_in[4];
  const float* b1_1 = (const float*)d_in[5];
  const float* a1_1 = (const float*)d_in[6];
  const float* W2_0 = (const float*)d_in[7];
  const float* b2_0 = (const float*)d_in[8];
  const float* a2_0 = (const float*)d_in[9];
  const float* W2_1 = (const float*)d_in[10];
  const float* b2_1 = (const float*)d_in[11];
  const float* a2_1 = (const float*)d_in[12];
  const int* src0 = (const int*)d_in[13];
  const int* dst0 = (const int*)d_in[14];
  const int* src1 = (const int*)d_in[15];
  const int* dst1 = (const int*)d_in[16];
  float* out = (float*)d_out;

  const int N = NNODES, E = NEDGES;

  char* w = (char*)d_ws;
  auto alloc = [&](size_t bytes) -> char* {
    char* p = w;
    w += (bytes + 255) & ~(size_t)255;
    return p;
  };
  int* row_off0 = (int*)alloc((N + 1) * sizeof(int));
  int* cur0     = (int*)alloc(N * sizeof(int));
  int* srt0     = (int*)alloc((size_t)E * sizeof(int));
  int* row_off1 = (int*)alloc((N + 1) * sizeof(int));
  int* cur1     = (int*)alloc(N * sizeof(int));
  int* srt1     = (int*)alloc((size_t)E * sizeof(int));
  float* Wh1_0  = (float*)alloc((size_t)N * 128 * sizeof(float));
  float* Wh1_1  = (float*)alloc((size_t)N * 128 * sizeof(float));
  float* h1     = (float*)alloc((size_t)N * 128 * sizeof(float));
  float* Wh2_0  = (float*)alloc((size_t)N * 64 * sizeof(float));
  float* Wh2_1  = (float*)alloc((size_t)N * 64 * sizeof(float));
  float* alA    = (float*)alloc(N * sizeof(float));
  float* arA    = (float*)alloc(N * sizeof(float));
  float* alB    = (float*)alloc(N * sizeof(float));
  float* arB    = (float*)alloc(N * sizeof(float));
  (void)ws_size;

  // ---- CSR build (used by both layers) ----
  hipMemsetAsync(cur0, 0, N * sizeof(int), stream);
  hipMemsetAsync(cur1, 0, N * sizeof(int), stream);
  int egrid = (E + 255) / 256;
  k_hist<<<egrid, 256, 0, stream>>>(dst0, cur0, E);
  k_hist<<<egrid, 256, 0, stream>>>(dst1, cur1, E);
  k_scan<<<1, 1024, 0, stream>>>(cur0, row_off0, cur0, N);
  k_scan<<<1, 1024, 0, stream>>>(cur1, row_off1, cur1, N);
  k_scatter<<<egrid, 256, 0, stream>>>(src0, dst0, cur0, srt0, E);
  k_scatter<<<egrid, 256, 0, stream>>>(src1, dst1, cur1, srt1, E);

  int ngrid4 = (N + 3) / 4;

  // ---- layer 1 (F = 128) ----
  {
    int ggrid = (N + 31) / 32;  // ROWS=32 for F=128
    k_gemm<128><<<ggrid, 256, 0, stream>>>(x, W1_0, b1_0, Wh1_0, N);
    k_gemm<128><<<ggrid, 256, 0, stream>>>(x, W1_1, b1_1, Wh1_1, N);
    k_rowdot<128><<<ngrid4, 256, 0, stream>>>(Wh1_0, a1_0, alA, arA, N);
    k_rowdot<128><<<ngrid4, 256, 0, stream>>>(Wh1_1, a1_1, alB, arB, N);
    k_agg<128, 0><<<ngrid4, 256, 0, stream>>>(row_off0, srt0, alA, arA, Wh1_0, h1, N);
    k_agg<128, 2><<<ngrid4, 256, 0, stream>>>(row_off1, srt1, alB, arB, Wh1_1, h1, N);
  }

  // ---- layer 2 (F = 64) ----
  {
    int ggrid = (N + 63) / 64;  // ROWS=64 for F=64
    k_gemm<64><<<ggrid, 256, 0, stream>>>(h1, W2_0, b2_0, Wh2_0, N);
    k_gemm<64><<<ggrid, 256, 0, stream>>>(h1, W2_1, b2_1, Wh2_1, N);
    k_rowdot<64><<<ngrid4, 256, 0, stream>>>(Wh2_0, a2_0, alA, arA, N);
    k_rowdot<64><<<ngrid4, 256, 0, stream>>>(Wh2_1, a2_1, alB, arB, N);
    k_agg<64, 0><<<ngrid4, 256, 0, stream>>>(row_off0, srt0, alA, arA, Wh2_0, out, N);
    k_agg<64, 1><<<ngrid4, 256, 0, stream>>>(row_off1, srt1, alB, arB, Wh2_1, out, N);
  }
}

// Round 3
// 405.443 us; speedup vs baseline: 1.5582x; 1.5582x over previous
//
#include <hip/hip_runtime.h>
#include <hip/hip_bf16.h>

#define NNODES 20000
#define NEDGES 500000
#define LRELU(v) ((v) > 0.f ? (v) : (v) * 0.01f)

// ---------------------------------------------------------------------------
// CSR build (both etypes per launch): histogram -> scan -> scatter
// ---------------------------------------------------------------------------
__global__ __launch_bounds__(256) void k_hist(const int* __restrict__ dst0,
                                              const int* __restrict__ dst1,
                                              int* __restrict__ deg, int ne,
                                              int n) {
  const int* dst = blockIdx.y ? dst1 : dst0;
  int* d = deg + blockIdx.y * n;
  int i = blockIdx.x * 256 + threadIdx.x;
  if (i < ne) atomicAdd(&d[dst[i]], 1);
}

// one block per etype; wave-shuffle scan, 4 barriers per 1024-chunk
__global__ __launch_bounds__(1024) void k_scan(int* __restrict__ cur,
                                               int* __restrict__ row_off,
                                               int n) {
  cur += blockIdx.x * n;
  row_off += blockIdx.x * (n + 1);
  __shared__ int wsum[16];
  __shared__ int sbase;
  int tid = threadIdx.x, wid = tid >> 6, lane = tid & 63;
  if (tid == 0) sbase = 0;
  __syncthreads();
  for (int start = 0; start < n; start += 1024) {
    int i = start + tid;
    int v = (i < n) ? cur[i] : 0;
    int x = v;
#pragma unroll
    for (int o = 1; o < 64; o <<= 1) {
      int t = __shfl_up(x, o);
      if (lane >= o) x += t;
    }
    if (lane == 63) wsum[wid] = x;
    __syncthreads();
    if (wid == 0) {
      int s = (lane < 16) ? wsum[lane] : 0;
#pragma unroll
      for (int o = 1; o < 16; o <<= 1) {
        int t = __shfl_up(s, o);
        if (lane >= o) s += t;
      }
      if (lane < 16) wsum[lane] = s;
    }
    __syncthreads();
    int base = sbase;
    int woff = wid ? wsum[wid - 1] : 0;
    if (i < n) {
      int excl = base + woff + x - v;
      row_off[i] = excl;
      cur[i] = excl;
    }
    __syncthreads();
    if (tid == 0) sbase = base + wsum[15];
    __syncthreads();
  }
  if (tid == 0) row_off[n] = sbase;
}

__global__ __launch_bounds__(256) void k_scatter(const int* __restrict__ src0,
                                                 const int* __restrict__ dst0,
                                                 const int* __restrict__ src1,
                                                 const int* __restrict__ dst1,
                                                 int* __restrict__ cursor,
                                                 int* __restrict__ srt0,
                                                 int* __restrict__ srt1, int ne,
                                                 int n) {
  const int* src = blockIdx.y ? src1 : src0;
  const int* dst = blockIdx.y ? dst1 : dst0;
  int* cur = cursor + blockIdx.y * n;
  int* srt = blockIdx.y ? srt1 : srt0;
  int i = blockIdx.x * 256 + threadIdx.x;
  if (i < ne) {
    int pos = atomicAdd(&cur[dst[i]], 1);
    srt[pos] = src[i];
  }
}

// ---------------------------------------------------------------------------
// GEMM + fused rowdot epilogue.  Y[m][o] = X[m][:].W[o][:] + b[o]  (K=128)
// al[m] = Y[m][:].a[0:F]   ar[m] = Y[m][:].a[F:2F]
// blockIdx.y selects etype parameter set.
// ---------------------------------------------------------------------------
template <int F>
__global__ __launch_bounds__(256) void k_gemm(
    const float* __restrict__ X, const float* __restrict__ W0p,
    const float* __restrict__ W1p, const float* __restrict__ b0p,
    const float* __restrict__ b1p, const float* __restrict__ a0p,
    const float* __restrict__ a1p, float* __restrict__ Y0p,
    float* __restrict__ Y1p, float* __restrict__ al0p,
    float* __restrict__ ar0p, float* __restrict__ al1p,
    float* __restrict__ ar1p, int nrows) {
  int t = blockIdx.y;
  const float* W = t ? W1p : W0p;
  const float* bias = t ? b1p : b0p;
  const float* a = t ? a1p : a0p;
  float* Y = t ? Y1p : Y0p;
  float* al = t ? al1p : al0p;
  float* ar = t ? ar1p : ar0p;

  constexpr int CG = F / 4;      // threads across cols
  constexpr int RG = 256 / CG;   // row groups
  constexpr int ROWS = RG * 4;
  __shared__ float xs[ROWS][129];
  __shared__ float wt[64][F];

  int tid = threadIdx.x;
  int r0 = blockIdx.x * ROWS;

  for (int idx = tid; idx < ROWS * 128; idx += 256) {
    int r = idx >> 7, k = idx & 127;
    int gr = r0 + r;
    xs[r][k] = (gr < nrows) ? X[gr * 128 + k] : 0.f;
  }

  int tc = tid % CG, tr = tid / CG;
  int lr = tr * 4, lc = tc * 4;
  float acc[4][4] = {};

  for (int kc = 0; kc < 2; ++kc) {
    __syncthreads();
    for (int idx = tid; idx < 64 * F; idx += 256) {
      int k = idx / F, o = idx % F;
      wt[k][o] = W[o * 128 + kc * 64 + k];
    }
    __syncthreads();
#pragma unroll 4
    for (int k = 0; k < 64; ++k) {
      float4 b4 = *(const float4*)&wt[k][lc];
#pragma unroll
      for (int r = 0; r < 4; ++r) {
        float av = xs[lr + r][kc * 64 + k];
        acc[r][0] += av * b4.x;
        acc[r][1] += av * b4.y;
        acc[r][2] += av * b4.z;
        acc[r][3] += av * b4.w;
      }
    }
  }

  float4 bb = *(const float4*)&bias[lc];
  float4 av_l = *(const float4*)&a[lc];
  float4 av_r = *(const float4*)&a[F + lc];
#pragma unroll
  for (int r = 0; r < 4; ++r) {
    int gr = r0 + lr + r;
    if (gr < nrows) {
      float4 o4 = make_float4(acc[r][0] + bb.x, acc[r][1] + bb.y,
                              acc[r][2] + bb.z, acc[r][3] + bb.w);
      *(float4*)&Y[(size_t)gr * F + lc] = o4;
      float pl = o4.x * av_l.x + o4.y * av_l.y + o4.z * av_l.z + o4.w * av_l.w;
      float pr = o4.x * av_r.x + o4.y * av_r.y + o4.z * av_r.z + o4.w * av_r.w;
#pragma unroll
      for (int o = CG / 2; o; o >>= 1) {
        pl += __shfl_xor(pl, o);
        pr += __shfl_xor(pr, o);
      }
      if (tc == 0) {
        al[gr] = pl;
        ar[gr] = pr;
      }
    }
  }
}

// ---------------------------------------------------------------------------
// Fused dual-etype aggregation. One wave per dst node; float4 per lane ->
// F/4 lanes per row, 64/(F/4) edge groups, 2x unrolled => 4-8 rows in flight.
// acc accumulates across both etypes (alpha already normalized per etype).
// ---------------------------------------------------------------------------
template <int F, bool FINAL_LRELU>
__global__ __launch_bounds__(256) void k_agg2(
    const int* __restrict__ row_off,  // [2*(n+1)]
    const int* __restrict__ srt0, const int* __restrict__ srt1,
    const float* __restrict__ al0, const float* __restrict__ ar0,
    const float* __restrict__ al1, const float* __restrict__ ar1,
    const float* __restrict__ Wh0, const float* __restrict__ Wh1,
    float* __restrict__ H, int n) {
  constexpr int G = F / 4;    // lanes per row
  constexpr int NG = 64 / G;  // edge groups per wave
  int wid = threadIdx.x >> 6, lane = threadIdx.x & 63;
  int d = blockIdx.x * 4 + wid;
  if (d >= n) return;
  int g = lane / G, lg = lane % G;
  float4 acc = make_float4(0.f, 0.f, 0.f, 0.f);

#pragma unroll
  for (int t = 0; t < 2; ++t) {
    const int* ro = row_off + t * (n + 1);
    const int* srt = t ? srt1 : srt0;
    const float* al = t ? al1 : al0;
    const float* ar = t ? ar1 : ar0;
    const float* Wh = t ? Wh1 : Wh0;
    int beg = ro[d], end = ro[d + 1];
    if (beg == end) continue;
    float ard = ar[d];

    float mx = -3.4e38f;
    for (int j = beg + lane; j < end; j += 64) {
      float e = al[srt[j]] + ard;
      mx = fmaxf(mx, LRELU(e));
    }
#pragma unroll
    for (int o = 32; o; o >>= 1) mx = fmaxf(mx, __shfl_xor(mx, o));

    float den = 0.f;
    for (int j = beg + lane; j < end; j += 64) {
      float e = al[srt[j]] + ard;
      den += __expf(LRELU(e) - mx);
    }
#pragma unroll
    for (int o = 32; o; o >>= 1) den += __shfl_xor(den, o);
    float rden = 1.f / den;

    int j = beg + g;
    for (; j + NG < end; j += 2 * NG) {
      int s0 = srt[j], s1 = srt[j + NG];
      float e0 = al[s0] + ard, e1 = al[s1] + ard;
      float w0 = __expf(LRELU(e0) - mx) * rden;
      float w1 = __expf(LRELU(e1) - mx) * rden;
      float4 v0 = *(const float4*)&Wh[(size_t)s0 * F + lg * 4];
      float4 v1 = *(const float4*)&Wh[(size_t)s1 * F + lg * 4];
      acc.x += w0 * v0.x + w1 * v1.x;
      acc.y += w0 * v0.y + w1 * v1.y;
      acc.z += w0 * v0.z + w1 * v1.z;
      acc.w += w0 * v0.w + w1 * v1.w;
    }
    if (j < end) {
      int s0 = srt[j];
      float e0 = al[s0] + ard;
      float w0 = __expf(LRELU(e0) - mx) * rden;
      float4 v0 = *(const float4*)&Wh[(size_t)s0 * F + lg * 4];
      acc.x += w0 * v0.x;
      acc.y += w0 * v0.y;
      acc.z += w0 * v0.z;
      acc.w += w0 * v0.w;
    }
  }

  // combine edge groups (NG=2: one xor; NG=4: two)
#pragma unroll
  for (int o = 32; o >= G; o >>= 1) {
    acc.x += __shfl_xor(acc.x, o);
    acc.y += __shfl_xor(acc.y, o);
    acc.z += __shfl_xor(acc.z, o);
    acc.w += __shfl_xor(acc.w, o);
  }
  if (g == 0) {
    if (FINAL_LRELU) {
      acc.x = LRELU(acc.x);
      acc.y = LRELU(acc.y);
      acc.z = LRELU(acc.z);
      acc.w = LRELU(acc.w);
    }
    *(float4*)&H[(size_t)d * F + lg * 4] = acc;
  }
}

// ---------------------------------------------------------------------------
// launch
// ---------------------------------------------------------------------------
extern "C" void kernel_launch(void* const* d_in, const int* in_sizes, int n_in,
                              void* d_out, int out_size, void* d_ws,
                              size_t ws_size, hipStream_t stream) {
  const float* x    = (const float*)d_in[0];
  const float* W1_0 = (const float*)d_in[1];
  const float* b1_0 = (const float*)d_in[2];
  const float* a1_0 = (const float*)d_in[3];
  const float* W1_1 = (const float*)d_in[4];
  const float* b1_1 = (const float*)d_in[5];
  const float* a1_1 = (const float*)d_in[6];
  const float* W2_0 = (const float*)d_in[7];
  const float* b2_0 = (const float*)d_in[8];
  const float* a2_0 = (const float*)d_in[9];
  const float* W2_1 = (const float*)d_in[10];
  const float* b2_1 = (const float*)d_in[11];
  const float* a2_1 = (const float*)d_in[12];
  const int* src0 = (const int*)d_in[13];
  const int* dst0 = (const int*)d_in[14];
  const int* src1 = (const int*)d_in[15];
  const int* dst1 = (const int*)d_in[16];
  float* out = (float*)d_out;

  const int N = NNODES, E = NEDGES;

  char* w = (char*)d_ws;
  auto alloc = [&](size_t bytes) -> char* {
    char* p = w;
    w += (bytes + 255) & ~(size_t)255;
    return p;
  };
  int* row_off = (int*)alloc(2 * (N + 1) * sizeof(int));
  int* cur     = (int*)alloc(2 * N * sizeof(int));
  int* srt0    = (int*)alloc((size_t)E * sizeof(int));
  int* srt1    = (int*)alloc((size_t)E * sizeof(int));
  float* Wh1_0 = (float*)alloc((size_t)N * 128 * sizeof(float));
  float* Wh1_1 = (float*)alloc((size_t)N * 128 * sizeof(float));
  float* h1    = (float*)alloc((size_t)N * 128 * sizeof(float));
  float* Wh2_0 = (float*)alloc((size_t)N * 64 * sizeof(float));
  float* Wh2_1 = (float*)alloc((size_t)N * 64 * sizeof(float));
  float* alA   = (float*)alloc(N * sizeof(float));
  float* arA   = (float*)alloc(N * sizeof(float));
  float* alB   = (float*)alloc(N * sizeof(float));
  float* arB   = (float*)alloc(N * sizeof(float));
  (void)ws_size;

  // ---- CSR build ----
  hipMemsetAsync(cur, 0, 2 * N * sizeof(int), stream);
  dim3 eg((E + 255) / 256, 2);
  k_hist<<<eg, 256, 0, stream>>>(dst0, dst1, cur, E, N);
  k_scan<<<2, 1024, 0, stream>>>(cur, row_off, N);
  k_scatter<<<eg, 256, 0, stream>>>(src0, dst0, src1, dst1, cur, srt0, srt1, E, N);

  int ngrid4 = (N + 3) / 4;

  // ---- layer 1 (F=128) ----
  dim3 g1((N + 31) / 32, 2);
  k_gemm<128><<<g1, 256, 0, stream>>>(x, W1_0, W1_1, b1_0, b1_1, a1_0, a1_1,
                                      Wh1_0, Wh1_1, alA, arA, alB, arB, N);
  k_agg2<128, true><<<ngrid4, 256, 0, stream>>>(row_off, srt0, srt1, alA, arA,
                                                alB, arB, Wh1_0, Wh1_1, h1, N);

  // ---- layer 2 (F=64) ----
  dim3 g2((N + 63) / 64, 2);
  k_gemm<64><<<g2, 256, 0, stream>>>(h1, W2_0, W2_1, b2_0, b2_1, a2_0, a2_1,
                                     Wh2_0, Wh2_1, alA, arA, alB, arB, N);
  k_agg2<64, false><<<ngrid4, 256, 0, stream>>>(row_off, srt0, srt1, alA, arA,
                                                alB, arB, Wh2_0, Wh2_1, out, N);
}

// Round 4
// 369.607 us; speedup vs baseline: 1.7093x; 1.0970x over previous
//
#include <hip/hip_runtime.h>
#include <hip/hip_bf16.h>

#define NNODES 20000
#define NEDGES 500000
#define LRELU(v) ((v) > 0.f ? (v) : (v) * 0.01f)

using bf16_t = __hip_bfloat16;
typedef __attribute__((ext_vector_type(8))) short bf16x8;  // 8 bf16 (4 VGPRs)
typedef __attribute__((ext_vector_type(4))) float f32x4;

// ---------------------------------------------------------------------------
// CSR build (both etypes per launch): histogram -> scan -> scatter
// ---------------------------------------------------------------------------
__global__ __launch_bounds__(256) void k_hist(const int* __restrict__ dst0,
                                              const int* __restrict__ dst1,
                                              int* __restrict__ deg, int ne,
                                              int n) {
  const int* dst = blockIdx.y ? dst1 : dst0;
  int* d = deg + blockIdx.y * n;
  int i = blockIdx.x * 256 + threadIdx.x;
  if (i < ne) atomicAdd(&d[dst[i]], 1);
}

// one block per etype; wave-shuffle scan
__global__ __launch_bounds__(1024) void k_scan(int* __restrict__ cur,
                                               int* __restrict__ row_off,
                                               int n) {
  cur += blockIdx.x * n;
  row_off += blockIdx.x * (n + 1);
  __shared__ int wsum[16];
  __shared__ int sbase;
  int tid = threadIdx.x, wid = tid >> 6, lane = tid & 63;
  if (tid == 0) sbase = 0;
  __syncthreads();
  for (int start = 0; start < n; start += 1024) {
    int i = start + tid;
    int v = (i < n) ? cur[i] : 0;
    int x = v;
#pragma unroll
    for (int o = 1; o < 64; o <<= 1) {
      int t = __shfl_up(x, o);
      if (lane >= o) x += t;
    }
    if (lane == 63) wsum[wid] = x;
    __syncthreads();
    if (wid == 0) {
      int s = (lane < 16) ? wsum[lane] : 0;
#pragma unroll
      for (int o = 1; o < 16; o <<= 1) {
        int t = __shfl_up(s, o);
        if (lane >= o) s += t;
      }
      if (lane < 16) wsum[lane] = s;
    }
    __syncthreads();
    int base = sbase;
    int woff = wid ? wsum[wid - 1] : 0;
    if (i < n) {
      int excl = base + woff + x - v;
      row_off[i] = excl;
      cur[i] = excl;
    }
    __syncthreads();
    if (tid == 0) sbase = base + wsum[15];
    __syncthreads();
  }
  if (tid == 0) row_off[n] = sbase;
}

__global__ __launch_bounds__(256) void k_scatter(const int* __restrict__ src0,
                                                 const int* __restrict__ dst0,
                                                 const int* __restrict__ src1,
                                                 const int* __restrict__ dst1,
                                                 int* __restrict__ cursor,
                                                 int* __restrict__ srt0,
                                                 int* __restrict__ srt1, int ne,
                                                 int n) {
  const int* src = blockIdx.y ? src1 : src0;
  const int* dst = blockIdx.y ? dst1 : dst0;
  int* cur = cursor + blockIdx.y * n;
  int* srt = blockIdx.y ? srt1 : srt0;
  int i = blockIdx.x * 256 + threadIdx.x;
  if (i < ne) {
    int pos = atomicAdd(&cur[dst[i]], 1);
    srt[pos] = src[i];
  }
}

// ---------------------------------------------------------------------------
// split fp32 -> bf16 hi + bf16 lo (lo = v - (float)hi), float4-vectorized
// ---------------------------------------------------------------------------
__global__ __launch_bounds__(256) void k_split(const float* __restrict__ in,
                                               bf16_t* __restrict__ hi,
                                               bf16_t* __restrict__ lo,
                                               int n4) {
  int i = blockIdx.x * 256 + threadIdx.x;
  if (i >= n4) return;
  float4 v = *(const float4*)&in[i * 4];
  bf16_t h0 = __float2bfloat16(v.x), h1 = __float2bfloat16(v.y);
  bf16_t h2 = __float2bfloat16(v.z), h3 = __float2bfloat16(v.w);
  hi[i * 4 + 0] = h0;
  hi[i * 4 + 1] = h1;
  hi[i * 4 + 2] = h2;
  hi[i * 4 + 3] = h3;
  lo[i * 4 + 0] = __float2bfloat16(v.x - __bfloat162float(h0));
  lo[i * 4 + 1] = __float2bfloat16(v.y - __bfloat162float(h1));
  lo[i * 4 + 2] = __float2bfloat16(v.z - __bfloat162float(h2));
  lo[i * 4 + 3] = __float2bfloat16(v.w - __bfloat162float(h3));
}

// ---------------------------------------------------------------------------
// MFMA GEMM, split-bf16 3-term (Ah*Bh + Ah*Bl + Al*Bh), fp32 accumulate.
// Wh[m][o] = x[m][:].W[o][:] + b[o]; K=128. Fused rowdot epilogue:
// al[m] = Wh[m][:].a[0:F], ar[m] = Wh[m][:].a[F:2F].
// Block: 256 thr = 4 waves; wave w owns rows row0+w*16..+15, all F cols.
// No LDS, no barriers: A/B frags are contiguous 16B global loads (L1/L2-hot).
// ---------------------------------------------------------------------------
template <int F>
__global__ __launch_bounds__(256) void k_gemm_mfma(
    const bf16_t* __restrict__ Xh, const bf16_t* __restrict__ Xl,
    const bf16_t* __restrict__ Wh0, const bf16_t* __restrict__ Wl0,
    const bf16_t* __restrict__ Wh1, const bf16_t* __restrict__ Wl1,
    const float* __restrict__ b0p, const float* __restrict__ b1p,
    const float* __restrict__ a0p, const float* __restrict__ a1p,
    float* __restrict__ Y0, float* __restrict__ Y1, float* __restrict__ al0,
    float* __restrict__ ar0, float* __restrict__ al1, float* __restrict__ ar1,
    int nrows) {
  constexpr int NT = F / 16;  // N tiles per wave
  int t = blockIdx.y;
  const bf16_t* Wgh = t ? Wh1 : Wh0;
  const bf16_t* Wgl = t ? Wl1 : Wl0;
  const float* bias = t ? b1p : b0p;
  const float* av = t ? a1p : a0p;
  float* Y = t ? Y1 : Y0;
  float* al = t ? al1 : al0;
  float* ar = t ? ar1 : ar0;

  int wid = threadIdx.x >> 6, lane = threadIdx.x & 63;
  int row0 = blockIdx.x * 64 + wid * 16;
  int cl = lane & 15, g4 = lane >> 4;
  int rA = row0 + cl;                 // A-row this lane loads
  int rAc = min(rA, nrows - 1);       // clamp for tail block

  f32x4 acc[NT] = {};

#pragma unroll
  for (int ks = 0; ks < 4; ++ks) {
    int k0 = ks * 32 + g4 * 8;
    bf16x8 Ah = *(const bf16x8*)&Xh[(size_t)rAc * 128 + k0];
    bf16x8 Al = *(const bf16x8*)&Xl[(size_t)rAc * 128 + k0];
#pragma unroll
    for (int nt = 0; nt < NT; ++nt) {
      size_t off = (size_t)(nt * 16 + cl) * 128 + k0;  // W row = output col
      bf16x8 Bh = *(const bf16x8*)&Wgh[off];
      bf16x8 Bl = *(const bf16x8*)&Wgl[off];
      acc[nt] = __builtin_amdgcn_mfma_f32_16x16x32_bf16(Ah, Bh, acc[nt], 0, 0, 0);
      acc[nt] = __builtin_amdgcn_mfma_f32_16x16x32_bf16(Ah, Bl, acc[nt], 0, 0, 0);
      acc[nt] = __builtin_amdgcn_mfma_f32_16x16x32_bf16(Al, Bh, acc[nt], 0, 0, 0);
    }
  }

  // epilogue: bias, store Wh, fused rowdot
  // C/D layout: col = cl (+tile), row = row0 + g4*4 + j   [m89/m91]
  float pl[4] = {}, pr[4] = {};
#pragma unroll
  for (int nt = 0; nt < NT; ++nt) {
    int c = nt * 16 + cl;
    float bv = bias[c], aL = av[c], aR = av[F + c];
#pragma unroll
    for (int j = 0; j < 4; ++j) {
      int r = row0 + g4 * 4 + j;
      float v = acc[nt][j] + bv;
      if (r < nrows) Y[(size_t)r * F + c] = v;
      pl[j] += v * aL;
      pr[j] += v * aR;
    }
  }
#pragma unroll
  for (int j = 0; j < 4; ++j) {
    float sl = pl[j], sr = pr[j];
#pragma unroll
    for (int o = 8; o; o >>= 1) {  // reduce across the 16 lanes sharing a row
      sl += __shfl_xor(sl, o);
      sr += __shfl_xor(sr, o);
    }
    int r = row0 + g4 * 4 + j;
    if (cl == 0 && r < nrows) {
      al[r] = sl;
      ar[r] = sr;
    }
  }
}

// ---------------------------------------------------------------------------
// Fused dual-etype aggregation. One wave per dst node; float4/lane.
// OMODE 0: write fp32 H (no lrelu). OMODE 1: lrelu then write split-bf16
// (Hh/Hl) for the next layer's MFMA GEMM.
// ---------------------------------------------------------------------------
template <int F, int OMODE>
__global__ __launch_bounds__(256) void k_agg2(
    const int* __restrict__ row_off,  // [2*(n+1)]
    const int* __restrict__ srt0, const int* __restrict__ srt1,
    const float* __restrict__ al0, const float* __restrict__ ar0,
    const float* __restrict__ al1, const float* __restrict__ ar1,
    const float* __restrict__ Wh0, const float* __restrict__ Wh1,
    float* __restrict__ H, bf16_t* __restrict__ Hh, bf16_t* __restrict__ Hl,
    int n) {
  constexpr int G = F / 4;    // lanes per row
  constexpr int NG = 64 / G;  // edge groups per wave
  int wid = threadIdx.x >> 6, lane = threadIdx.x & 63;
  int d = blockIdx.x * 4 + wid;
  if (d >= n) return;
  int g = lane / G, lg = lane % G;
  float4 acc = make_float4(0.f, 0.f, 0.f, 0.f);

#pragma unroll
  for (int t = 0; t < 2; ++t) {
    const int* ro = row_off + t * (n + 1);
    const int* srt = t ? srt1 : srt0;
    const float* al = t ? al1 : al0;
    const float* ar = t ? ar1 : ar0;
    const float* Wh = t ? Wh1 : Wh0;
    int beg = ro[d], end = ro[d + 1];
    if (beg == end) continue;
    float ard = ar[d];

    float mx = -3.4e38f;
    for (int j = beg + lane; j < end; j += 64) {
      float e = al[srt[j]] + ard;
      mx = fmaxf(mx, LRELU(e));
    }
#pragma unroll
    for (int o = 32; o; o >>= 1) mx = fmaxf(mx, __shfl_xor(mx, o));

    float den = 0.f;
    for (int j = beg + lane; j < end; j += 64) {
      float e = al[srt[j]] + ard;
      den += __expf(LRELU(e) - mx);
    }
#pragma unroll
    for (int o = 32; o; o >>= 1) den += __shfl_xor(den, o);
    float rden = 1.f / den;

    int j = beg + g;
    for (; j + NG < end; j += 2 * NG) {
      int s0 = srt[j], s1 = srt[j + NG];
      float e0 = al[s0] + ard, e1 = al[s1] + ard;
      float w0 = __expf(LRELU(e0) - mx) * rden;
      float w1 = __expf(LRELU(e1) - mx) * rden;
      float4 v0 = *(const float4*)&Wh[(size_t)s0 * F + lg * 4];
      float4 v1 = *(const float4*)&Wh[(size_t)s1 * F + lg * 4];
      acc.x += w0 * v0.x + w1 * v1.x;
      acc.y += w0 * v0.y + w1 * v1.y;
      acc.z += w0 * v0.z + w1 * v1.z;
      acc.w += w0 * v0.w + w1 * v1.w;
    }
    if (j < end) {
      int s0 = srt[j];
      float e0 = al[s0] + ard;
      float w0 = __expf(LRELU(e0) - mx) * rden;
      float4 v0 = *(const float4*)&Wh[(size_t)s0 * F + lg * 4];
      acc.x += w0 * v0.x;
      acc.y += w0 * v0.y;
      acc.z += w0 * v0.z;
      acc.w += w0 * v0.w;
    }
  }

#pragma unroll
  for (int o = 32; o >= G; o >>= 1) {
    acc.x += __shfl_xor(acc.x, o);
    acc.y += __shfl_xor(acc.y, o);
    acc.z += __shfl_xor(acc.z, o);
    acc.w += __shfl_xor(acc.w, o);
  }
  if (g == 0) {
    if (OMODE == 0) {
      *(float4*)&H[(size_t)d * F + lg * 4] = acc;
    } else {
      float vv[4] = {LRELU(acc.x), LRELU(acc.y), LRELU(acc.z), LRELU(acc.w)};
#pragma unroll
      for (int q = 0; q < 4; ++q) {
        bf16_t h = __float2bfloat16(vv[q]);
        Hh[(size_t)d * F + lg * 4 + q] = h;
        Hl[(size_t)d * F + lg * 4 + q] =
            __float2bfloat16(vv[q] - __bfloat162float(h));
      }
    }
  }
}

// ---------------------------------------------------------------------------
// launch
// ---------------------------------------------------------------------------
extern "C" void kernel_launch(void* const* d_in, const int* in_sizes, int n_in,
                              void* d_out, int out_size, void* d_ws,
                              size_t ws_size, hipStream_t stream) {
  const float* x    = (const float*)d_in[0];
  const float* W1_0 = (const float*)d_in[1];
  const float* b1_0 = (const float*)d_in[2];
  const float* a1_0 = (const float*)d_in[3];
  const float* W1_1 = (const float*)d_in[4];
  const float* b1_1 = (const float*)d_in[5];
  const float* a1_1 = (const float*)d_in[6];
  const float* W2_0 = (const float*)d_in[7];
  const float* b2_0 = (const float*)d_in[8];
  const float* a2_0 = (const float*)d_in[9];
  const float* W2_1 = (const float*)d_in[10];
  const float* b2_1 = (const float*)d_in[11];
  const float* a2_1 = (const float*)d_in[12];
  const int* src0 = (const int*)d_in[13];
  const int* dst0 = (const int*)d_in[14];
  const int* src1 = (const int*)d_in[15];
  const int* dst1 = (const int*)d_in[16];
  float* out = (float*)d_out;

  const int N = NNODES, E = NEDGES;

  char* w = (char*)d_ws;
  auto alloc = [&](size_t bytes) -> char* {
    char* p = w;
    w += (bytes + 255) & ~(size_t)255;
    return p;
  };
  int* row_off = (int*)alloc(2 * (N + 1) * sizeof(int));
  int* cur     = (int*)alloc(2 * N * sizeof(int));
  int* srt0    = (int*)alloc((size_t)E * sizeof(int));
  int* srt1    = (int*)alloc((size_t)E * sizeof(int));
  bf16_t* xh   = (bf16_t*)alloc((size_t)N * 128 * 2);
  bf16_t* xl   = (bf16_t*)alloc((size_t)N * 128 * 2);
  float* Wh1_0 = (float*)alloc((size_t)N * 128 * 4);
  float* Wh1_1 = (float*)alloc((size_t)N * 128 * 4);
  bf16_t* h1h  = (bf16_t*)alloc((size_t)N * 128 * 2);
  bf16_t* h1l  = (bf16_t*)alloc((size_t)N * 128 * 2);
  bf16_t* w1h0 = (bf16_t*)alloc(128 * 128 * 2);
  bf16_t* w1l0 = (bf16_t*)alloc(128 * 128 * 2);
  bf16_t* w1h1 = (bf16_t*)alloc(128 * 128 * 2);
  bf16_t* w1l1 = (bf16_t*)alloc(128 * 128 * 2);
  bf16_t* w2h0 = (bf16_t*)alloc(64 * 128 * 2);
  bf16_t* w2l0 = (bf16_t*)alloc(64 * 128 * 2);
  bf16_t* w2h1 = (bf16_t*)alloc(64 * 128 * 2);
  bf16_t* w2l1 = (bf16_t*)alloc(64 * 128 * 2);
  float* alA   = (float*)alloc(N * sizeof(float));
  float* arA   = (float*)alloc(N * sizeof(float));
  float* alB   = (float*)alloc(N * sizeof(float));
  float* arB   = (float*)alloc(N * sizeof(float));
  // Wh2 aliases xh/xl: xh/xl dead after layer-1 GEMM; sizes match (5.12 MB).
  float* Wh2_0 = (float*)xh;
  float* Wh2_1 = (float*)xl;
  (void)ws_size;

  // ---- CSR build ----
  hipMemsetAsync(cur, 0, 2 * N * sizeof(int), stream);
  dim3 eg((E + 255) / 256, 2);
  k_hist<<<eg, 256, 0, stream>>>(dst0, dst1, cur, E, N);
  k_scan<<<2, 1024, 0, stream>>>(cur, row_off, N);
  k_scatter<<<eg, 256, 0, stream>>>(src0, dst0, src1, dst1, cur, srt0, srt1, E, N);

  // ---- input/weight splits ----
  k_split<<<(N * 128 / 4 + 255) / 256, 256, 0, stream>>>(x, xh, xl, N * 128 / 4);
  k_split<<<(128 * 128 / 4 + 255) / 256, 256, 0, stream>>>(W1_0, w1h0, w1l0, 128 * 128 / 4);
  k_split<<<(128 * 128 / 4 + 255) / 256, 256, 0, stream>>>(W1_1, w1h1, w1l1, 128 * 128 / 4);
  k_split<<<(64 * 128 / 4 + 255) / 256, 256, 0, stream>>>(W2_0, w2h0, w2l0, 64 * 128 / 4);
  k_split<<<(64 * 128 / 4 + 255) / 256, 256, 0, stream>>>(W2_1, w2h1, w2l1, 64 * 128 / 4);

  int ngrid4 = (N + 3) / 4;
  dim3 gg((N + 63) / 64, 2);

  // ---- layer 1 (F=128) ----
  k_gemm_mfma<128><<<gg, 256, 0, stream>>>(xh, xl, w1h0, w1l0, w1h1, w1l1,
                                           b1_0, b1_1, a1_0, a1_1, Wh1_0,
                                           Wh1_1, alA, arA, alB, arB, N);
  k_agg2<128, 1><<<ngrid4, 256, 0, stream>>>(row_off, srt0, srt1, alA, arA,
                                             alB, arB, Wh1_0, Wh1_1, nullptr,
                                             h1h, h1l, N);

  // ---- layer 2 (F=64) ----
  k_gemm_mfma<64><<<gg, 256, 0, stream>>>(h1h, h1l, w2h0, w2l0, w2h1, w2l1,
                                          b2_0, b2_1, a2_0, a2_1, Wh2_0,
                                          Wh2_1, alA, arA, alB, arB, N);
  k_agg2<64, 0><<<ngrid4, 256, 0, stream>>>(row_off, srt0, srt1, alA, arA,
                                            alB, arB, Wh2_0, Wh2_1, out,
                                            nullptr, nullptr, N);
}

// Round 5
// 333.678 us; speedup vs baseline: 1.8933x; 1.1077x over previous
//
#include <hip/hip_runtime.h>
#include <hip/hip_bf16.h>

#define NNODES 20000
#define NEDGES 500000
#define LRELU(v) ((v) > 0.f ? (v) : (v) * 0.01f)

using bf16_t = __hip_bfloat16;
typedef __attribute__((ext_vector_type(8))) short bf16x8;  // 8 bf16 (4 VGPRs)
typedef __attribute__((ext_vector_type(4))) float f32x4;

__device__ inline float bf2f(short u) {
  unsigned int i = ((unsigned int)(unsigned short)u) << 16;
  float f;
  __builtin_memcpy(&f, &i, 4);
  return f;
}

// ---------------------------------------------------------------------------
// CSR build (both etypes per launch): histogram -> scan -> scatter
// ---------------------------------------------------------------------------
__global__ __launch_bounds__(256) void k_hist(const int* __restrict__ dst0,
                                              const int* __restrict__ dst1,
                                              int* __restrict__ deg, int ne,
                                              int n) {
  const int* dst = blockIdx.y ? dst1 : dst0;
  int* d = deg + blockIdx.y * n;
  int i = blockIdx.x * 256 + threadIdx.x;
  if (i < ne) atomicAdd(&d[dst[i]], 1);
}

__global__ __launch_bounds__(1024) void k_scan(int* __restrict__ cur,
                                               int* __restrict__ row_off,
                                               int n) {
  cur += blockIdx.x * n;
  row_off += blockIdx.x * (n + 1);
  __shared__ int wsum[16];
  __shared__ int sbase;
  int tid = threadIdx.x, wid = tid >> 6, lane = tid & 63;
  if (tid == 0) sbase = 0;
  __syncthreads();
  for (int start = 0; start < n; start += 1024) {
    int i = start + tid;
    int v = (i < n) ? cur[i] : 0;
    int x = v;
#pragma unroll
    for (int o = 1; o < 64; o <<= 1) {
      int t = __shfl_up(x, o);
      if (lane >= o) x += t;
    }
    if (lane == 63) wsum[wid] = x;
    __syncthreads();
    if (wid == 0) {
      int s = (lane < 16) ? wsum[lane] : 0;
#pragma unroll
      for (int o = 1; o < 16; o <<= 1) {
        int t = __shfl_up(s, o);
        if (lane >= o) s += t;
      }
      if (lane < 16) wsum[lane] = s;
    }
    __syncthreads();
    int base = sbase;
    int woff = wid ? wsum[wid - 1] : 0;
    if (i < n) {
      int excl = base + woff + x - v;
      row_off[i] = excl;
      cur[i] = excl;
    }
    __syncthreads();
    if (tid == 0) sbase = base + wsum[15];
    __syncthreads();
  }
  if (tid == 0) row_off[n] = sbase;
}

__global__ __launch_bounds__(256) void k_scatter(const int* __restrict__ src0,
                                                 const int* __restrict__ dst0,
                                                 const int* __restrict__ src1,
                                                 const int* __restrict__ dst1,
                                                 int* __restrict__ cursor,
                                                 int* __restrict__ srt0,
                                                 int* __restrict__ srt1, int ne,
                                                 int n) {
  const int* src = blockIdx.y ? src1 : src0;
  const int* dst = blockIdx.y ? dst1 : dst0;
  int* cur = cursor + blockIdx.y * n;
  int* srt = blockIdx.y ? srt1 : srt0;
  int i = blockIdx.x * 256 + threadIdx.x;
  if (i < ne) {
    int pos = atomicAdd(&cur[dst[i]], 1);
    srt[pos] = src[i];
  }
}

// ---------------------------------------------------------------------------
// split fp32 -> bf16 hi + bf16 lo
// ---------------------------------------------------------------------------
__global__ __launch_bounds__(256) void k_split(const float* __restrict__ in,
                                               bf16_t* __restrict__ hi,
                                               bf16_t* __restrict__ lo,
                                               int n4) {
  int i = blockIdx.x * 256 + threadIdx.x;
  if (i >= n4) return;
  float4 v = *(const float4*)&in[i * 4];
  bf16_t h0 = __float2bfloat16(v.x), h1 = __float2bfloat16(v.y);
  bf16_t h2 = __float2bfloat16(v.z), h3 = __float2bfloat16(v.w);
  hi[i * 4 + 0] = h0;
  hi[i * 4 + 1] = h1;
  hi[i * 4 + 2] = h2;
  hi[i * 4 + 3] = h3;
  lo[i * 4 + 0] = __float2bfloat16(v.x - __bfloat162float(h0));
  lo[i * 4 + 1] = __float2bfloat16(v.y - __bfloat162float(h1));
  lo[i * 4 + 2] = __float2bfloat16(v.z - __bfloat162float(h2));
  lo[i * 4 + 3] = __float2bfloat16(v.w - __bfloat162float(h3));
}

// ---------------------------------------------------------------------------
// MFMA GEMM, split-bf16 3-term, fp32 accumulate, fused rowdot epilogue.
// YBF16: store Y as bf16 (layer-1, gathered in bf16 by agg) else fp32.
// ---------------------------------------------------------------------------
template <int F, bool YBF16>
__global__ __launch_bounds__(256) void k_gemm_mfma(
    const bf16_t* __restrict__ Xh, const bf16_t* __restrict__ Xl,
    const bf16_t* __restrict__ Wh0, const bf16_t* __restrict__ Wl0,
    const bf16_t* __restrict__ Wh1, const bf16_t* __restrict__ Wl1,
    const float* __restrict__ b0p, const float* __restrict__ b1p,
    const float* __restrict__ a0p, const float* __restrict__ a1p,
    void* __restrict__ Y0, void* __restrict__ Y1, float* __restrict__ al0,
    float* __restrict__ ar0, float* __restrict__ al1, float* __restrict__ ar1,
    int nrows) {
  constexpr int NT = F / 16;
  int t = blockIdx.y;
  const bf16_t* Wgh = t ? Wh1 : Wh0;
  const bf16_t* Wgl = t ? Wl1 : Wl0;
  const float* bias = t ? b1p : b0p;
  const float* av = t ? a1p : a0p;
  void* Y = t ? Y1 : Y0;
  float* al = t ? al1 : al0;
  float* ar = t ? ar1 : ar0;

  int wid = threadIdx.x >> 6, lane = threadIdx.x & 63;
  int row0 = blockIdx.x * 64 + wid * 16;
  int cl = lane & 15, g4 = lane >> 4;
  int rA = row0 + cl;
  int rAc = min(rA, nrows - 1);

  f32x4 acc[NT] = {};

#pragma unroll
  for (int ks = 0; ks < 4; ++ks) {
    int k0 = ks * 32 + g4 * 8;
    bf16x8 Ah = *(const bf16x8*)&Xh[(size_t)rAc * 128 + k0];
    bf16x8 Al = *(const bf16x8*)&Xl[(size_t)rAc * 128 + k0];
#pragma unroll
    for (int nt = 0; nt < NT; ++nt) {
      size_t off = (size_t)(nt * 16 + cl) * 128 + k0;
      bf16x8 Bh = *(const bf16x8*)&Wgh[off];
      bf16x8 Bl = *(const bf16x8*)&Wgl[off];
      acc[nt] = __builtin_amdgcn_mfma_f32_16x16x32_bf16(Ah, Bh, acc[nt], 0, 0, 0);
      acc[nt] = __builtin_amdgcn_mfma_f32_16x16x32_bf16(Ah, Bl, acc[nt], 0, 0, 0);
      acc[nt] = __builtin_amdgcn_mfma_f32_16x16x32_bf16(Al, Bh, acc[nt], 0, 0, 0);
    }
  }

  // C/D layout: col = nt*16+cl, row = row0 + g4*4 + j   [m89/m91]
  float pl[4] = {}, pr[4] = {};
#pragma unroll
  for (int nt = 0; nt < NT; ++nt) {
    int c = nt * 16 + cl;
    float bv = bias[c], aL = av[c], aR = av[F + c];
#pragma unroll
    for (int j = 0; j < 4; ++j) {
      int r = row0 + g4 * 4 + j;
      float v = acc[nt][j] + bv;
      if (r < nrows) {
        if (YBF16)
          ((bf16_t*)Y)[(size_t)r * F + c] = __float2bfloat16(v);
        else
          ((float*)Y)[(size_t)r * F + c] = v;
      }
      pl[j] += v * aL;
      pr[j] += v * aR;
    }
  }
#pragma unroll
  for (int j = 0; j < 4; ++j) {
    float sl = pl[j], sr = pr[j];
#pragma unroll
    for (int o = 8; o; o >>= 1) {
      sl += __shfl_xor(sl, o);
      sr += __shfl_xor(sr, o);
    }
    int r = row0 + g4 * 4 + j;
    if (cl == 0 && r < nrows) {
      al[r] = sl;
      ar[r] = sr;
    }
  }
}

// ---------------------------------------------------------------------------
// Fused dual-etype aggregation, SINGLE-PASS softmax (no max subtraction:
// logits ~N(0,1), clamped at 70, exp cannot overflow fp32).
// 16 lanes/row x 16B/lane (256B rows: F=128 bf16 or F=64 fp32), 4 edge
// groups/wave, 2x unroll => 8 rows in flight.
// BG: gather bf16. OMODE 0: write fp32 H. OMODE 1: lrelu + split-bf16 out.
// ---------------------------------------------------------------------------
template <int F, bool BG, int OMODE>
__global__ __launch_bounds__(256) void k_agg2(
    const int* __restrict__ row_off, const int* __restrict__ srt0,
    const int* __restrict__ srt1, const float* __restrict__ al0,
    const float* __restrict__ ar0, const float* __restrict__ al1,
    const float* __restrict__ ar1, const void* __restrict__ Wg0,
    const void* __restrict__ Wg1, float* __restrict__ H,
    bf16_t* __restrict__ Hh, bf16_t* __restrict__ Hl, int n) {
  constexpr int VE = F / 16;  // features per lane (8 bf16 or 4 f32)
  int wid = threadIdx.x >> 6, lane = threadIdx.x & 63;
  int d = blockIdx.x * 4 + wid;
  if (d >= n) return;
  int g = lane >> 4, cl = lane & 15;
  float acc[VE] = {};

#pragma unroll
  for (int t = 0; t < 2; ++t) {
    const int* ro = row_off + t * (n + 1);
    const int* srt = t ? srt1 : srt0;
    const float* al = t ? al1 : al0;
    const float* ar = t ? ar1 : ar0;
    const void* Wg = t ? Wg1 : Wg0;
    int beg = ro[d], end = ro[d + 1];
    if (beg == end) continue;
    float ard = ar[d];

    float denT = 0.f;
    float accT[VE] = {};
    int j = beg + g;
    for (; j + 4 < end; j += 8) {
      int s0 = srt[j], s1 = srt[j + 4];
      float e0 = fminf(LRELU(al[s0] + ard), 70.f);
      float e1 = fminf(LRELU(al[s1] + ard), 70.f);
      float w0 = __expf(e0), w1 = __expf(e1);
      denT += w0 + w1;
      if (BG) {
        bf16x8 r0 = *(const bf16x8*)&((const bf16_t*)Wg)[(size_t)s0 * F + cl * 8];
        bf16x8 r1 = *(const bf16x8*)&((const bf16_t*)Wg)[(size_t)s1 * F + cl * 8];
#pragma unroll
        for (int v = 0; v < VE; ++v)
          accT[v] += w0 * bf2f(r0[v]) + w1 * bf2f(r1[v]);
      } else {
        float4 r0 = *(const float4*)&((const float*)Wg)[(size_t)s0 * F + cl * 4];
        float4 r1 = *(const float4*)&((const float*)Wg)[(size_t)s1 * F + cl * 4];
        accT[0] += w0 * r0.x + w1 * r1.x;
        accT[1] += w0 * r0.y + w1 * r1.y;
        accT[2] += w0 * r0.z + w1 * r1.z;
        accT[3] += w0 * r0.w + w1 * r1.w;
      }
    }
    for (; j < end; j += 4) {
      int s0 = srt[j];
      float e0 = fminf(LRELU(al[s0] + ard), 70.f);
      float w0 = __expf(e0);
      denT += w0;
      if (BG) {
        bf16x8 r0 = *(const bf16x8*)&((const bf16_t*)Wg)[(size_t)s0 * F + cl * 8];
#pragma unroll
        for (int v = 0; v < VE; ++v) accT[v] += w0 * bf2f(r0[v]);
      } else {
        float4 r0 = *(const float4*)&((const float*)Wg)[(size_t)s0 * F + cl * 4];
        accT[0] += w0 * r0.x;
        accT[1] += w0 * r0.y;
        accT[2] += w0 * r0.z;
        accT[3] += w0 * r0.w;
      }
    }

    // merge the 4 edge groups, normalize by this etype's denom
#pragma unroll
    for (int o = 32; o >= 16; o >>= 1) {
      denT += __shfl_xor(denT, o);
#pragma unroll
      for (int v = 0; v < VE; ++v) accT[v] += __shfl_xor(accT[v], o);
    }
    float rden = 1.f / denT;
#pragma unroll
    for (int v = 0; v < VE; ++v) acc[v] += accT[v] * rden;
  }

  if (g == 0) {
    if (OMODE == 0) {
      float4 o4 = make_float4(acc[0], acc[1], acc[2], acc[3]);
      *(float4*)&H[(size_t)d * F + cl * 4] = o4;
    } else {
      bf16x8 hv, lv;
#pragma unroll
      for (int q = 0; q < VE; ++q) {
        float v = LRELU(acc[q]);
        bf16_t h = __float2bfloat16(v);
        bf16_t l = __float2bfloat16(v - __bfloat162float(h));
        short hb, lb;
        __builtin_memcpy(&hb, &h, 2);
        __builtin_memcpy(&lb, &l, 2);
        hv[q] = hb;
        lv[q] = lb;
      }
      *(bf16x8*)&Hh[(size_t)d * F + cl * 8] = hv;
      *(bf16x8*)&Hl[(size_t)d * F + cl * 8] = lv;
    }
  }
}

// ---------------------------------------------------------------------------
// launch
// ---------------------------------------------------------------------------
extern "C" void kernel_launch(void* const* d_in, const int* in_sizes, int n_in,
                              void* d_out, int out_size, void* d_ws,
                              size_t ws_size, hipStream_t stream) {
  const float* x    = (const float*)d_in[0];
  const float* W1_0 = (const float*)d_in[1];
  const float* b1_0 = (const float*)d_in[2];
  const float* a1_0 = (const float*)d_in[3];
  const float* W1_1 = (const float*)d_in[4];
  const float* b1_1 = (const float*)d_in[5];
  const float* a1_1 = (const float*)d_in[6];
  const float* W2_0 = (const float*)d_in[7];
  const float* b2_0 = (const float*)d_in[8];
  const float* a2_0 = (const float*)d_in[9];
  const float* W2_1 = (const float*)d_in[10];
  const float* b2_1 = (const float*)d_in[11];
  const float* a2_1 = (const float*)d_in[12];
  const int* src0 = (const int*)d_in[13];
  const int* dst0 = (const int*)d_in[14];
  const int* src1 = (const int*)d_in[15];
  const int* dst1 = (const int*)d_in[16];
  float* out = (float*)d_out;

  const int N = NNODES, E = NEDGES;

  char* w = (char*)d_ws;
  auto alloc = [&](size_t bytes) -> char* {
    char* p = w;
    w += (bytes + 255) & ~(size_t)255;
    return p;
  };
  int* row_off = (int*)alloc(2 * (N + 1) * sizeof(int));
  int* cur     = (int*)alloc(2 * N * sizeof(int));
  int* srt0    = (int*)alloc((size_t)E * sizeof(int));
  int* srt1    = (int*)alloc((size_t)E * sizeof(int));
  bf16_t* xh   = (bf16_t*)alloc((size_t)N * 128 * 2);
  bf16_t* xl   = (bf16_t*)alloc((size_t)N * 128 * 2);
  bf16_t* Whb_0 = (bf16_t*)alloc((size_t)N * 128 * 2);  // layer-1 Wh, bf16
  bf16_t* Whb_1 = (bf16_t*)alloc((size_t)N * 128 * 2);
  bf16_t* h1h  = (bf16_t*)alloc((size_t)N * 128 * 2);
  bf16_t* h1l  = (bf16_t*)alloc((size_t)N * 128 * 2);
  bf16_t* w1h0 = (bf16_t*)alloc(128 * 128 * 2);
  bf16_t* w1l0 = (bf16_t*)alloc(128 * 128 * 2);
  bf16_t* w1h1 = (bf16_t*)alloc(128 * 128 * 2);
  bf16_t* w1l1 = (bf16_t*)alloc(128 * 128 * 2);
  bf16_t* w2h0 = (bf16_t*)alloc(64 * 128 * 2);
  bf16_t* w2l0 = (bf16_t*)alloc(64 * 128 * 2);
  bf16_t* w2h1 = (bf16_t*)alloc(64 * 128 * 2);
  bf16_t* w2l1 = (bf16_t*)alloc(64 * 128 * 2);
  float* Wh2_0 = (float*)alloc((size_t)N * 64 * 4);  // layer-2 Wh, fp32
  float* Wh2_1 = (float*)alloc((size_t)N * 64 * 4);
  float* alA   = (float*)alloc(N * sizeof(float));
  float* arA   = (float*)alloc(N * sizeof(float));
  float* alB   = (float*)alloc(N * sizeof(float));
  float* arB   = (float*)alloc(N * sizeof(float));
  (void)ws_size;

  // ---- CSR build ----
  hipMemsetAsync(cur, 0, 2 * N * sizeof(int), stream);
  dim3 eg((E + 255) / 256, 2);
  k_hist<<<eg, 256, 0, stream>>>(dst0, dst1, cur, E, N);
  k_scan<<<2, 1024, 0, stream>>>(cur, row_off, N);
  k_scatter<<<eg, 256, 0, stream>>>(src0, dst0, src1, dst1, cur, srt0, srt1, E, N);

  // ---- input/weight splits ----
  k_split<<<(N * 128 / 4 + 255) / 256, 256, 0, stream>>>(x, xh, xl, N * 128 / 4);
  k_split<<<(128 * 128 / 4 + 255) / 256, 256, 0, stream>>>(W1_0, w1h0, w1l0, 128 * 128 / 4);
  k_split<<<(128 * 128 / 4 + 255) / 256, 256, 0, stream>>>(W1_1, w1h1, w1l1, 128 * 128 / 4);
  k_split<<<(64 * 128 / 4 + 255) / 256, 256, 0, stream>>>(W2_0, w2h0, w2l0, 64 * 128 / 4);
  k_split<<<(64 * 128 / 4 + 255) / 256, 256, 0, stream>>>(W2_1, w2h1, w2l1, 64 * 128 / 4);

  int ngrid4 = (N + 3) / 4;
  dim3 gg((N + 63) / 64, 2);

  // ---- layer 1 (F=128, bf16 Wh + bf16 gather) ----
  k_gemm_mfma<128, true><<<gg, 256, 0, stream>>>(
      xh, xl, w1h0, w1l0, w1h1, w1l1, b1_0, b1_1, a1_0, a1_1, Whb_0, Whb_1,
      alA, arA, alB, arB, N);
  k_agg2<128, true, 1><<<ngrid4, 256, 0, stream>>>(
      row_off, srt0, srt1, alA, arA, alB, arB, Whb_0, Whb_1, nullptr, h1h,
      h1l, N);

  // ---- layer 2 (F=64, fp32 Wh + fp32 gather) ----
  k_gemm_mfma<64, false><<<gg, 256, 0, stream>>>(
      h1h, h1l, w2h0, w2l0, w2h1, w2l1, b2_0, b2_1, a2_0, a2_1, Wh2_0, Wh2_1,
      alA, arA, alB, arB, N);
  k_agg2<64, false, 0><<<ngrid4, 256, 0, stream>>>(
      row_off, srt0, srt1, alA, arA, alB, arB, Wh2_0, Wh2_1, out, nullptr,
      nullptr, N);
}

// Round 6
// 274.403 us; speedup vs baseline: 2.3023x; 1.2160x over previous
//
#include <hip/hip_runtime.h>
#include <hip/hip_bf16.h>

#define NNODES 20000
#define NEDGES 500000
#define LRELU(v) ((v) > 0.f ? (v) : (v) * 0.01f)

using bf16_t = __hip_bfloat16;
typedef __attribute__((ext_vector_type(8))) short bf16x8;  // 8 bf16 (4 VGPRs)
typedef __attribute__((ext_vector_type(4))) float f32x4;

__device__ inline float bf2f(short u) {
  unsigned int i = ((unsigned int)(unsigned short)u) << 16;
  float f;
  __builtin_memcpy(&f, &i, 4);
  return f;
}

// ---------------------------------------------------------------------------
// CSR build: (1) fused histogram+position, (2) fast scan, (3) atomic-free
// scatter. srt/pos are ushort (src < 20000, max degree << 65536).
// ---------------------------------------------------------------------------
__global__ __launch_bounds__(256) void k_histpos(const int* __restrict__ dst0,
                                                 const int* __restrict__ dst1,
                                                 int* __restrict__ deg,
                                                 unsigned short* __restrict__ pos0,
                                                 unsigned short* __restrict__ pos1,
                                                 int ne, int n) {
  const int* dst = blockIdx.y ? dst1 : dst0;
  unsigned short* pos = blockIdx.y ? pos1 : pos0;
  int* d = deg + blockIdx.y * n;
  int i = blockIdx.x * 256 + threadIdx.x;
  if (i < ne) pos[i] = (unsigned short)atomicAdd(&d[dst[i]], 1);
}

// one block per etype; 20 elems/thread serial + single wave/LDS scan pass
__global__ __launch_bounds__(1024) void k_scan(const int* __restrict__ deg,
                                               int* __restrict__ row_off,
                                               int n) {
  deg += blockIdx.x * n;
  row_off += blockIdx.x * (n + 1);
  constexpr int PT = 20;  // 1024*20 = 20480 >= n
  __shared__ int wsum[16];
  int tid = threadIdx.x, wid = tid >> 6, lane = tid & 63;
  int base_i = tid * PT;
  int v[PT];
  int s = 0;
#pragma unroll
  for (int q = 0; q < PT; ++q) {
    int i = base_i + q;
    v[q] = (i < n) ? deg[i] : 0;
    s += v[q];
  }
  int x = s;
#pragma unroll
  for (int o = 1; o < 64; o <<= 1) {
    int t = __shfl_up(x, o);
    if (lane >= o) x += t;
  }
  if (lane == 63) wsum[wid] = x;
  __syncthreads();
  if (wid == 0) {
    int ws = (lane < 16) ? wsum[lane] : 0;
#pragma unroll
    for (int o = 1; o < 16; o <<= 1) {
      int t = __shfl_up(ws, o);
      if (lane >= o) ws += t;
    }
    if (lane < 16) wsum[lane] = ws;
  }
  __syncthreads();
  int run = (wid ? wsum[wid - 1] : 0) + (x - s);  // exclusive prefix
#pragma unroll
  for (int q = 0; q < PT; ++q) {
    int i = base_i + q;
    if (i < n) row_off[i] = run;
    run += v[q];
  }
  if (tid == 1023) row_off[n] = run;
}

__global__ __launch_bounds__(256) void k_scatter(
    const int* __restrict__ src0, const int* __restrict__ dst0,
    const int* __restrict__ src1, const int* __restrict__ dst1,
    const unsigned short* __restrict__ pos0,
    const unsigned short* __restrict__ pos1, const int* __restrict__ row_off,
    unsigned short* __restrict__ srt0, unsigned short* __restrict__ srt1,
    int ne, int n) {
  const int* src = blockIdx.y ? src1 : src0;
  const int* dst = blockIdx.y ? dst1 : dst0;
  const unsigned short* pos = blockIdx.y ? pos1 : pos0;
  const int* ro = row_off + blockIdx.y * (n + 1);
  unsigned short* srt = blockIdx.y ? srt1 : srt0;
  int i = blockIdx.x * 256 + threadIdx.x;
  if (i < ne) {
    int dd = dst[i];
    srt[ro[dd] + (int)pos[i]] = (unsigned short)src[i];
  }
}

// ---------------------------------------------------------------------------
// split fp32 -> bf16 hi + bf16 lo
// ---------------------------------------------------------------------------
__global__ __launch_bounds__(256) void k_split(const float* __restrict__ in,
                                               bf16_t* __restrict__ hi,
                                               bf16_t* __restrict__ lo,
                                               int n4) {
  int i = blockIdx.x * 256 + threadIdx.x;
  if (i >= n4) return;
  float4 v = *(const float4*)&in[i * 4];
  bf16_t h0 = __float2bfloat16(v.x), h1 = __float2bfloat16(v.y);
  bf16_t h2 = __float2bfloat16(v.z), h3 = __float2bfloat16(v.w);
  hi[i * 4 + 0] = h0;
  hi[i * 4 + 1] = h1;
  hi[i * 4 + 2] = h2;
  hi[i * 4 + 3] = h3;
  lo[i * 4 + 0] = __float2bfloat16(v.x - __bfloat162float(h0));
  lo[i * 4 + 1] = __float2bfloat16(v.y - __bfloat162float(h1));
  lo[i * 4 + 2] = __float2bfloat16(v.z - __bfloat162float(h2));
  lo[i * 4 + 3] = __float2bfloat16(v.w - __bfloat162float(h3));
}

// ---------------------------------------------------------------------------
// MFMA GEMM, split-bf16 3-term, fp32 accumulate, fused rowdot epilogue.
// Y stored bf16 (gathered in bf16 by agg).
// ---------------------------------------------------------------------------
template <int F>
__global__ __launch_bounds__(256) void k_gemm_mfma(
    const bf16_t* __restrict__ Xh, const bf16_t* __restrict__ Xl,
    const bf16_t* __restrict__ Wh0, const bf16_t* __restrict__ Wl0,
    const bf16_t* __restrict__ Wh1, const bf16_t* __restrict__ Wl1,
    const float* __restrict__ b0p, const float* __restrict__ b1p,
    const float* __restrict__ a0p, const float* __restrict__ a1p,
    bf16_t* __restrict__ Y0, bf16_t* __restrict__ Y1, float* __restrict__ al0,
    float* __restrict__ ar0, float* __restrict__ al1, float* __restrict__ ar1,
    int nrows) {
  constexpr int NT = F / 16;
  int t = blockIdx.y;
  const bf16_t* Wgh = t ? Wh1 : Wh0;
  const bf16_t* Wgl = t ? Wl1 : Wl0;
  const float* bias = t ? b1p : b0p;
  const float* av = t ? a1p : a0p;
  bf16_t* Y = t ? Y1 : Y0;
  float* al = t ? al1 : al0;
  float* ar = t ? ar1 : ar0;

  int wid = threadIdx.x >> 6, lane = threadIdx.x & 63;
  int row0 = blockIdx.x * 64 + wid * 16;
  int cl = lane & 15, g4 = lane >> 4;
  int rA = row0 + cl;
  int rAc = min(rA, nrows - 1);

  f32x4 acc[NT] = {};

#pragma unroll
  for (int ks = 0; ks < 4; ++ks) {
    int k0 = ks * 32 + g4 * 8;
    bf16x8 Ah = *(const bf16x8*)&Xh[(size_t)rAc * 128 + k0];
    bf16x8 Al = *(const bf16x8*)&Xl[(size_t)rAc * 128 + k0];
#pragma unroll
    for (int nt = 0; nt < NT; ++nt) {
      size_t off = (size_t)(nt * 16 + cl) * 128 + k0;
      bf16x8 Bh = *(const bf16x8*)&Wgh[off];
      bf16x8 Bl = *(const bf16x8*)&Wgl[off];
      acc[nt] = __builtin_amdgcn_mfma_f32_16x16x32_bf16(Ah, Bh, acc[nt], 0, 0, 0);
      acc[nt] = __builtin_amdgcn_mfma_f32_16x16x32_bf16(Ah, Bl, acc[nt], 0, 0, 0);
      acc[nt] = __builtin_amdgcn_mfma_f32_16x16x32_bf16(Al, Bh, acc[nt], 0, 0, 0);
    }
  }

  // C/D layout: col = nt*16+cl, row = row0 + g4*4 + j   [m89/m91]
  float pl[4] = {}, pr[4] = {};
#pragma unroll
  for (int nt = 0; nt < NT; ++nt) {
    int c = nt * 16 + cl;
    float bv = bias[c], aL = av[c], aR = av[F + c];
#pragma unroll
    for (int j = 0; j < 4; ++j) {
      int r = row0 + g4 * 4 + j;
      float v = acc[nt][j] + bv;
      if (r < nrows) Y[(size_t)r * F + c] = __float2bfloat16(v);
      pl[j] += v * aL;
      pr[j] += v * aR;
    }
  }
#pragma unroll
  for (int j = 0; j < 4; ++j) {
    float sl = pl[j], sr = pr[j];
#pragma unroll
    for (int o = 8; o; o >>= 1) {
      sl += __shfl_xor(sl, o);
      sr += __shfl_xor(sr, o);
    }
    int r = row0 + g4 * 4 + j;
    if (cl == 0 && r < nrows) {
      al[r] = sl;
      ar[r] = sr;
    }
  }
}

// ---------------------------------------------------------------------------
// Fused dual-etype aggregation, single-pass softmax, bf16 gather.
// LPR lanes/row (16B each), 64/LPR edge groups, 2x unroll.
// OMODE 0: write fp32 H. OMODE 1: lrelu + split-bf16 out.
// ---------------------------------------------------------------------------
template <int F, int OMODE>
__global__ __launch_bounds__(256) void k_agg2(
    const int* __restrict__ row_off, const unsigned short* __restrict__ srt0,
    const unsigned short* __restrict__ srt1, const float* __restrict__ al0,
    const float* __restrict__ ar0, const float* __restrict__ al1,
    const float* __restrict__ ar1, const bf16_t* __restrict__ Wg0,
    const bf16_t* __restrict__ Wg1, float* __restrict__ H,
    bf16_t* __restrict__ Hh, bf16_t* __restrict__ Hl, int n) {
  constexpr int LPR = (F * 2) / 16;  // lanes per row (16B per lane)
  constexpr int NGR = 64 / LPR;      // edge groups per wave
  constexpr int VE = F / LPR;        // elements per lane (= 8)
  int wid = threadIdx.x >> 6, lane = threadIdx.x & 63;
  int d = blockIdx.x * 4 + wid;
  if (d >= n) return;
  int g = lane / LPR, cl = lane % LPR;
  float acc[VE] = {};

#pragma unroll
  for (int t = 0; t < 2; ++t) {
    const int* ro = row_off + t * (n + 1);
    const unsigned short* srt = t ? srt1 : srt0;
    const float* al = t ? al1 : al0;
    const float* ar = t ? ar1 : ar0;
    const bf16_t* Wg = t ? Wg1 : Wg0;
    int beg = ro[d], end = ro[d + 1];
    if (beg == end) continue;
    float ard = ar[d];

    float denT = 0.f;
    float accT[VE] = {};
    int j = beg + g;
    for (; j + NGR < end; j += 2 * NGR) {
      int s0 = srt[j], s1 = srt[j + NGR];
      float e0 = fminf(LRELU(al[s0] + ard), 70.f);
      float e1 = fminf(LRELU(al[s1] + ard), 70.f);
      float w0 = __expf(e0), w1 = __expf(e1);
      denT += w0 + w1;
      bf16x8 r0 = *(const bf16x8*)&Wg[(size_t)s0 * F + cl * 8];
      bf16x8 r1 = *(const bf16x8*)&Wg[(size_t)s1 * F + cl * 8];
#pragma unroll
      for (int v = 0; v < VE; ++v)
        accT[v] += w0 * bf2f(r0[v]) + w1 * bf2f(r1[v]);
    }
    if (j < end) {
      int s0 = srt[j];
      float e0 = fminf(LRELU(al[s0] + ard), 70.f);
      float w0 = __expf(e0);
      denT += w0;
      bf16x8 r0 = *(const bf16x8*)&Wg[(size_t)s0 * F + cl * 8];
#pragma unroll
      for (int v = 0; v < VE; ++v) accT[v] += w0 * bf2f(r0[v]);
    }

    // merge edge groups, normalize by this etype's denom
#pragma unroll
    for (int o = 32; o >= LPR; o >>= 1) {
      denT += __shfl_xor(denT, o);
#pragma unroll
      for (int v = 0; v < VE; ++v) accT[v] += __shfl_xor(accT[v], o);
    }
    float rden = 1.f / denT;
#pragma unroll
    for (int v = 0; v < VE; ++v) acc[v] += accT[v] * rden;
  }

  if (g == 0) {
    if (OMODE == 0) {
#pragma unroll
      for (int q = 0; q < VE; q += 4) {
        float4 o4 = make_float4(acc[q], acc[q + 1], acc[q + 2], acc[q + 3]);
        *(float4*)&H[(size_t)d * F + cl * VE + q] = o4;
      }
    } else {
      bf16x8 hv, lv;
#pragma unroll
      for (int q = 0; q < VE; ++q) {
        float v = LRELU(acc[q]);
        bf16_t h = __float2bfloat16(v);
        bf16_t l = __float2bfloat16(v - __bfloat162float(h));
        short hb, lb;
        __builtin_memcpy(&hb, &h, 2);
        __builtin_memcpy(&lb, &l, 2);
        hv[q] = hb;
        lv[q] = lb;
      }
      *(bf16x8*)&Hh[(size_t)d * F + cl * 8] = hv;
      *(bf16x8*)&Hl[(size_t)d * F + cl * 8] = lv;
    }
  }
}

// ---------------------------------------------------------------------------
// launch
// ---------------------------------------------------------------------------
extern "C" void kernel_launch(void* const* d_in, const int* in_sizes, int n_in,
                              void* d_out, int out_size, void* d_ws,
                              size_t ws_size, hipStream_t stream) {
  const float* x    = (const float*)d_in[0];
  const float* W1_0 = (const float*)d_in[1];
  const float* b1_0 = (const float*)d_in[2];
  const float* a1_0 = (const float*)d_in[3];
  const float* W1_1 = (const float*)d_in[4];
  const float* b1_1 = (const float*)d_in[5];
  const float* a1_1 = (const float*)d_in[6];
  const float* W2_0 = (const float*)d_in[7];
  const float* b2_0 = (const float*)d_in[8];
  const float* a2_0 = (const float*)d_in[9];
  const float* W2_1 = (const float*)d_in[10];
  const float* b2_1 = (const float*)d_in[11];
  const float* a2_1 = (const float*)d_in[12];
  const int* src0 = (const int*)d_in[13];
  const int* dst0 = (const int*)d_in[14];
  const int* src1 = (const int*)d_in[15];
  const int* dst1 = (const int*)d_in[16];
  float* out = (float*)d_out;

  const int N = NNODES, E = NEDGES;
  typedef unsigned short u16;

  char* w = (char*)d_ws;
  auto alloc = [&](size_t bytes) -> char* {
    char* p = w;
    w += (bytes + 255) & ~(size_t)255;
    return p;
  };
  int* row_off = (int*)alloc(2 * (N + 1) * sizeof(int));
  int* deg     = (int*)alloc(2 * N * sizeof(int));
  u16* pos0    = (u16*)alloc((size_t)E * 2);
  u16* pos1    = (u16*)alloc((size_t)E * 2);
  u16* srt0    = (u16*)alloc((size_t)E * 2);
  u16* srt1    = (u16*)alloc((size_t)E * 2);
  bf16_t* xh   = (bf16_t*)alloc((size_t)N * 128 * 2);
  bf16_t* xl   = (bf16_t*)alloc((size_t)N * 128 * 2);
  bf16_t* Whb_0 = (bf16_t*)alloc((size_t)N * 128 * 2);
  bf16_t* Whb_1 = (bf16_t*)alloc((size_t)N * 128 * 2);
  bf16_t* h1h  = (bf16_t*)alloc((size_t)N * 128 * 2);
  bf16_t* h1l  = (bf16_t*)alloc((size_t)N * 128 * 2);
  bf16_t* w1h0 = (bf16_t*)alloc(128 * 128 * 2);
  bf16_t* w1l0 = (bf16_t*)alloc(128 * 128 * 2);
  bf16_t* w1h1 = (bf16_t*)alloc(128 * 128 * 2);
  bf16_t* w1l1 = (bf16_t*)alloc(128 * 128 * 2);
  bf16_t* w2h0 = (bf16_t*)alloc(64 * 128 * 2);
  bf16_t* w2l0 = (bf16_t*)alloc(64 * 128 * 2);
  bf16_t* w2h1 = (bf16_t*)alloc(64 * 128 * 2);
  bf16_t* w2l1 = (bf16_t*)alloc(64 * 128 * 2);
  bf16_t* Wh2b_0 = (bf16_t*)alloc((size_t)N * 64 * 2);
  bf16_t* Wh2b_1 = (bf16_t*)alloc((size_t)N * 64 * 2);
  float* alA   = (float*)alloc(N * sizeof(float));
  float* arA   = (float*)alloc(N * sizeof(float));
  float* alB   = (float*)alloc(N * sizeof(float));
  float* arB   = (float*)alloc(N * sizeof(float));
  (void)ws_size;

  // ---- CSR build ----
  hipMemsetAsync(deg, 0, 2 * N * sizeof(int), stream);
  dim3 eg((E + 255) / 256, 2);
  k_histpos<<<eg, 256, 0, stream>>>(dst0, dst1, deg, pos0, pos1, E, N);
  k_scan<<<2, 1024, 0, stream>>>(deg, row_off, N);
  k_scatter<<<eg, 256, 0, stream>>>(src0, dst0, src1, dst1, pos0, pos1,
                                    row_off, srt0, srt1, E, N);

  // ---- input/weight splits ----
  k_split<<<(N * 128 / 4 + 255) / 256, 256, 0, stream>>>(x, xh, xl, N * 128 / 4);
  k_split<<<(128 * 128 / 4 + 255) / 256, 256, 0, stream>>>(W1_0, w1h0, w1l0, 128 * 128 / 4);
  k_split<<<(128 * 128 / 4 + 255) / 256, 256, 0, stream>>>(W1_1, w1h1, w1l1, 128 * 128 / 4);
  k_split<<<(64 * 128 / 4 + 255) / 256, 256, 0, stream>>>(W2_0, w2h0, w2l0, 64 * 128 / 4);
  k_split<<<(64 * 128 / 4 + 255) / 256, 256, 0, stream>>>(W2_1, w2h1, w2l1, 64 * 128 / 4);

  int ngrid4 = (N + 3) / 4;
  dim3 gg((N + 63) / 64, 2);

  // ---- layer 1 (F=128, bf16 Wh + bf16 gather) ----
  k_gemm_mfma<128><<<gg, 256, 0, stream>>>(
      xh, xl, w1h0, w1l0, w1h1, w1l1, b1_0, b1_1, a1_0, a1_1, Whb_0, Whb_1,
      alA, arA, alB, arB, N);
  k_agg2<128, 1><<<ngrid4, 256, 0, stream>>>(
      row_off, srt0, srt1, alA, arA, alB, arB, Whb_0, Whb_1, nullptr, h1h,
      h1l, N);

  // ---- layer 2 (F=64, bf16 Wh + bf16 gather, fp32 out) ----
  k_gemm_mfma<64><<<gg, 256, 0, stream>>>(
      h1h, h1l, w2h0, w2l0, w2h1, w2l1, b2_0, b2_1, a2_0, a2_1, Wh2b_0,
      Wh2b_1, alA, arA, alB, arB, N);
  k_agg2<64, 0><<<ngrid4, 256, 0, stream>>>(
      row_off, srt0, srt1, alA, arA, alB, arB, Wh2b_0, Wh2b_1, out, nullptr,
      nullptr, N);
}

// Round 7
// 257.297 us; speedup vs baseline: 2.4554x; 1.0665x over previous
//
#include <hip/hip_runtime.h>
#include <hip/hip_bf16.h>

#define NNODES 20000
#define NEDGES 500000
#define LRELU(v) ((v) > 0.f ? (v) : (v) * 0.01f)

using bf16_t = __hip_bfloat16;
typedef unsigned short u16;
typedef __attribute__((ext_vector_type(8))) short bf16x8;  // 8 bf16 (4 VGPRs)
typedef __attribute__((ext_vector_type(4))) float f32x4;

__device__ inline float bf2f(short u) {
  unsigned int i = ((unsigned int)(unsigned short)u) << 16;
  float f;
  __builtin_memcpy(&f, &i, 4);
  return f;
}

// block-count constants
constexpr int HB = (NEDGES + 255) / 256;          // 1954 histpos/scatter blocks per etype
constexpr int SBX = (NNODES * 128 / 4 + 255) / 256;  // 2500 split-x blocks
constexpr int SBW1 = (128 * 128 / 4 + 255) / 256;    // 16
constexpr int SBW2 = (64 * 128 / 4 + 255) / 256;     // 8
constexpr int GB = (NNODES + 63) / 64;               // 313 gemm blocks per etype

// ---------------------------------------------------------------------------
// role bodies
// ---------------------------------------------------------------------------
__device__ inline void histpos_body(int bb, int t, const int* dst0,
                                    const int* dst1, int* deg, u16* pos0,
                                    u16* pos1) {
  const int* dst = t ? dst1 : dst0;
  u16* pos = t ? pos1 : pos0;
  int* d = deg + t * NNODES;
  int i = bb * 256 + threadIdx.x;
  if (i < NEDGES) pos[i] = (u16)atomicAdd(&d[dst[i]], 1);
}

__device__ inline void split_body(const float* in, bf16_t* hi, bf16_t* lo,
                                  int i, int n4) {
  if (i >= n4) return;
  float4 v = *(const float4*)&in[i * 4];
  bf16_t h0 = __float2bfloat16(v.x), h1 = __float2bfloat16(v.y);
  bf16_t h2 = __float2bfloat16(v.z), h3 = __float2bfloat16(v.w);
  hi[i * 4 + 0] = h0;
  hi[i * 4 + 1] = h1;
  hi[i * 4 + 2] = h2;
  hi[i * 4 + 3] = h3;
  lo[i * 4 + 0] = __float2bfloat16(v.x - __bfloat162float(h0));
  lo[i * 4 + 1] = __float2bfloat16(v.y - __bfloat162float(h1));
  lo[i * 4 + 2] = __float2bfloat16(v.z - __bfloat162float(h2));
  lo[i * 4 + 3] = __float2bfloat16(v.w - __bfloat162float(h3));
}

__device__ inline void scatter_body(int bb, int t, const int* src0,
                                    const int* dst0, const int* src1,
                                    const int* dst1, const u16* pos0,
                                    const u16* pos1, const int* row_off,
                                    u16* srt0, u16* srt1) {
  const int* src = t ? src1 : src0;
  const int* dst = t ? dst1 : dst0;
  const u16* pos = t ? pos1 : pos0;
  const int* ro = row_off + t * (NNODES + 1);
  u16* srt = t ? srt1 : srt0;
  int i = bb * 256 + threadIdx.x;
  if (i < NEDGES) {
    int dd = dst[i];
    srt[ro[dd] + (int)pos[i]] = (u16)src[i];
  }
}

// MFMA GEMM, split-bf16 3-term, fp32 accumulate, fused rowdot epilogue.
template <int F>
__device__ inline void gemm_body(
    int bx, int t, const bf16_t* Xh, const bf16_t* Xl, const bf16_t* Wh0,
    const bf16_t* Wl0, const bf16_t* Wh1, const bf16_t* Wl1, const float* b0p,
    const float* b1p, const float* a0p, const float* a1p, bf16_t* Y0,
    bf16_t* Y1, float* al0, float* ar0, float* al1, float* ar1, int nrows) {
  constexpr int NT = F / 16;
  const bf16_t* Wgh = t ? Wh1 : Wh0;
  const bf16_t* Wgl = t ? Wl1 : Wl0;
  const float* bias = t ? b1p : b0p;
  const float* av = t ? a1p : a0p;
  bf16_t* Y = t ? Y1 : Y0;
  float* al = t ? al1 : al0;
  float* ar = t ? ar1 : ar0;

  int wid = threadIdx.x >> 6, lane = threadIdx.x & 63;
  int row0 = bx * 64 + wid * 16;
  int cl = lane & 15, g4 = lane >> 4;
  int rAc = min(row0 + cl, nrows - 1);

  f32x4 acc[NT] = {};

#pragma unroll
  for (int ks = 0; ks < 4; ++ks) {
    int k0 = ks * 32 + g4 * 8;
    bf16x8 Ah = *(const bf16x8*)&Xh[(size_t)rAc * 128 + k0];
    bf16x8 Al = *(const bf16x8*)&Xl[(size_t)rAc * 128 + k0];
#pragma unroll
    for (int nt = 0; nt < NT; ++nt) {
      size_t off = (size_t)(nt * 16 + cl) * 128 + k0;
      bf16x8 Bh = *(const bf16x8*)&Wgh[off];
      bf16x8 Bl = *(const bf16x8*)&Wgl[off];
      acc[nt] = __builtin_amdgcn_mfma_f32_16x16x32_bf16(Ah, Bh, acc[nt], 0, 0, 0);
      acc[nt] = __builtin_amdgcn_mfma_f32_16x16x32_bf16(Ah, Bl, acc[nt], 0, 0, 0);
      acc[nt] = __builtin_amdgcn_mfma_f32_16x16x32_bf16(Al, Bh, acc[nt], 0, 0, 0);
    }
  }

  // C/D layout: col = nt*16+cl, row = row0 + g4*4 + j   [m89/m91]
  float pl[4] = {}, pr[4] = {};
#pragma unroll
  for (int nt = 0; nt < NT; ++nt) {
    int c = nt * 16 + cl;
    float bv = bias[c], aL = av[c], aR = av[F + c];
#pragma unroll
    for (int j = 0; j < 4; ++j) {
      int r = row0 + g4 * 4 + j;
      float v = acc[nt][j] + bv;
      if (r < nrows) Y[(size_t)r * F + c] = __float2bfloat16(v);
      pl[j] += v * aL;
      pr[j] += v * aR;
    }
  }
#pragma unroll
  for (int j = 0; j < 4; ++j) {
    float sl = pl[j], sr = pr[j];
#pragma unroll
    for (int o = 8; o; o >>= 1) {
      sl += __shfl_xor(sl, o);
      sr += __shfl_xor(sr, o);
    }
    int r = row0 + g4 * 4 + j;
    if (cl == 0 && r < nrows) {
      al[r] = sl;
      ar[r] = sr;
    }
  }
}

// ---------------------------------------------------------------------------
// L1: histogram+pos (atomic-bound) || all fp32->bf16hi/lo splits (BW-bound)
// ---------------------------------------------------------------------------
__global__ __launch_bounds__(256) void k_pre(
    const int* __restrict__ dst0, const int* __restrict__ dst1,
    int* __restrict__ deg, u16* __restrict__ pos0, u16* __restrict__ pos1,
    const float* __restrict__ x, bf16_t* __restrict__ xh,
    bf16_t* __restrict__ xl, const float* __restrict__ W1_0,
    bf16_t* __restrict__ w1h0, bf16_t* __restrict__ w1l0,
    const float* __restrict__ W1_1, bf16_t* __restrict__ w1h1,
    bf16_t* __restrict__ w1l1, const float* __restrict__ W2_0,
    bf16_t* __restrict__ w2h0, bf16_t* __restrict__ w2l0,
    const float* __restrict__ W2_1, bf16_t* __restrict__ w2h1,
    bf16_t* __restrict__ w2l1) {
  int b = blockIdx.x;
  if (b < 2 * HB) {
    histpos_body(b >= HB ? b - HB : b, b >= HB, dst0, dst1, deg, pos0, pos1);
    return;
  }
  b -= 2 * HB;
  int tid = threadIdx.x;
  if (b < SBX) { split_body(x, xh, xl, b * 256 + tid, NNODES * 128 / 4); return; }
  b -= SBX;
  if (b < SBW1) { split_body(W1_0, w1h0, w1l0, b * 256 + tid, 128 * 128 / 4); return; }
  b -= SBW1;
  if (b < SBW1) { split_body(W1_1, w1h1, w1l1, b * 256 + tid, 128 * 128 / 4); return; }
  b -= SBW1;
  if (b < SBW2) { split_body(W2_0, w2h0, w2l0, b * 256 + tid, 64 * 128 / 4); return; }
  b -= SBW2;
  split_body(W2_1, w2h1, w2l1, b * 256 + tid, 64 * 128 / 4);
}

// ---------------------------------------------------------------------------
// L2: scan (one block per etype; 20 elems/thread + wave/LDS scan)
// ---------------------------------------------------------------------------
__global__ __launch_bounds__(1024) void k_scan(const int* __restrict__ deg,
                                               int* __restrict__ row_off,
                                               int n) {
  deg += blockIdx.x * n;
  row_off += blockIdx.x * (n + 1);
  constexpr int PT = 20;
  __shared__ int wsum[16];
  int tid = threadIdx.x, wid = tid >> 6, lane = tid & 63;
  int base_i = tid * PT;
  int v[PT];
  int s = 0;
#pragma unroll
  for (int q = 0; q < PT; ++q) {
    int i = base_i + q;
    v[q] = (i < n) ? deg[i] : 0;
    s += v[q];
  }
  int x = s;
#pragma unroll
  for (int o = 1; o < 64; o <<= 1) {
    int t = __shfl_up(x, o);
    if (lane >= o) x += t;
  }
  if (lane == 63) wsum[wid] = x;
  __syncthreads();
  if (wid == 0) {
    int ws = (lane < 16) ? wsum[lane] : 0;
#pragma unroll
    for (int o = 1; o < 16; o <<= 1) {
      int t = __shfl_up(ws, o);
      if (lane >= o) ws += t;
    }
    if (lane < 16) wsum[lane] = ws;
  }
  __syncthreads();
  int run = (wid ? wsum[wid - 1] : 0) + (x - s);
#pragma unroll
  for (int q = 0; q < PT; ++q) {
    int i = base_i + q;
    if (i < n) row_off[i] = run;
    run += v[q];
  }
  if (tid == 1023) row_off[n] = run;
}

// ---------------------------------------------------------------------------
// L3: gemm1 (both etypes, MFMA-bound, blocks first) || scatter (latency)
// ---------------------------------------------------------------------------
__global__ __launch_bounds__(256) void k_mid(
    const bf16_t* __restrict__ xh, const bf16_t* __restrict__ xl,
    const bf16_t* __restrict__ w1h0, const bf16_t* __restrict__ w1l0,
    const bf16_t* __restrict__ w1h1, const bf16_t* __restrict__ w1l1,
    const float* __restrict__ b1_0, const float* __restrict__ b1_1,
    const float* __restrict__ a1_0, const float* __restrict__ a1_1,
    bf16_t* __restrict__ Whb_0, bf16_t* __restrict__ Whb_1,
    float* __restrict__ alA, float* __restrict__ arA, float* __restrict__ alB,
    float* __restrict__ arB, const int* __restrict__ src0,
    const int* __restrict__ dst0, const int* __restrict__ src1,
    const int* __restrict__ dst1, const u16* __restrict__ pos0,
    const u16* __restrict__ pos1, const int* __restrict__ row_off,
    u16* __restrict__ srt0, u16* __restrict__ srt1) {
  int b = blockIdx.x;
  if (b < 2 * GB) {
    gemm_body<128>(b >= GB ? b - GB : b, b >= GB, xh, xl, w1h0, w1l0, w1h1,
                   w1l1, b1_0, b1_1, a1_0, a1_1, Whb_0, Whb_1, alA, arA, alB,
                   arB, NNODES);
    return;
  }
  b -= 2 * GB;
  scatter_body(b >= HB ? b - HB : b, b >= HB, src0, dst0, src1, dst1, pos0,
               pos1, row_off, srt0, srt1);
}

// ---------------------------------------------------------------------------
// L5: gemm2 wrapper
// ---------------------------------------------------------------------------
__global__ __launch_bounds__(256) void k_gemm64(
    const bf16_t* __restrict__ Xh, const bf16_t* __restrict__ Xl,
    const bf16_t* __restrict__ w2h0, const bf16_t* __restrict__ w2l0,
    const bf16_t* __restrict__ w2h1, const bf16_t* __restrict__ w2l1,
    const float* __restrict__ b2_0, const float* __restrict__ b2_1,
    const float* __restrict__ a2_0, const float* __restrict__ a2_1,
    bf16_t* __restrict__ Y0, bf16_t* __restrict__ Y1, float* __restrict__ al0,
    float* __restrict__ ar0, float* __restrict__ al1,
    float* __restrict__ ar1) {
  gemm_body<64>(blockIdx.x, blockIdx.y, Xh, Xl, w2h0, w2l0, w2h1, w2l1, b2_0,
                b2_1, a2_0, a2_1, Y0, Y1, al0, ar0, al1, ar1, NNODES);
}

// ---------------------------------------------------------------------------
// Fused dual-etype aggregation, single-pass softmax, bf16 gather.
// ---------------------------------------------------------------------------
template <int F, int OMODE>
__global__ __launch_bounds__(256) void k_agg2(
    const int* __restrict__ row_off, const u16* __restrict__ srt0,
    const u16* __restrict__ srt1, const float* __restrict__ al0,
    const float* __restrict__ ar0, const float* __restrict__ al1,
    const float* __restrict__ ar1, const bf16_t* __restrict__ Wg0,
    const bf16_t* __restrict__ Wg1, float* __restrict__ H,
    bf16_t* __restrict__ Hh, bf16_t* __restrict__ Hl, int n) {
  constexpr int LPR = (F * 2) / 16;  // lanes per row (16B per lane)
  constexpr int NGR = 64 / LPR;      // edge groups per wave
  constexpr int VE = F / LPR;        // elements per lane (= 8)
  int wid = threadIdx.x >> 6, lane = threadIdx.x & 63;
  int d = blockIdx.x * 4 + wid;
  if (d >= n) return;
  int g = lane / LPR, cl = lane % LPR;
  float acc[VE] = {};

#pragma unroll
  for (int t = 0; t < 2; ++t) {
    const int* ro = row_off + t * (n + 1);
    const u16* srt = t ? srt1 : srt0;
    const float* al = t ? al1 : al0;
    const float* ar = t ? ar1 : ar0;
    const bf16_t* Wg = t ? Wg1 : Wg0;
    int beg = ro[d], end = ro[d + 1];
    if (beg == end) continue;
    float ard = ar[d];

    float denT = 0.f;
    float accT[VE] = {};
    int j = beg + g;
    for (; j + NGR < end; j += 2 * NGR) {
      int s0 = srt[j], s1 = srt[j + NGR];
      float e0 = fminf(LRELU(al[s0] + ard), 70.f);
      float e1 = fminf(LRELU(al[s1] + ard), 70.f);
      float w0 = __expf(e0), w1 = __expf(e1);
      denT += w0 + w1;
      bf16x8 r0 = *(const bf16x8*)&Wg[(size_t)s0 * F + cl * 8];
      bf16x8 r1 = *(const bf16x8*)&Wg[(size_t)s1 * F + cl * 8];
#pragma unroll
      for (int v = 0; v < VE; ++v)
        accT[v] += w0 * bf2f(r0[v]) + w1 * bf2f(r1[v]);
    }
    if (j < end) {
      int s0 = srt[j];
      float e0 = fminf(LRELU(al[s0] + ard), 70.f);
      float w0 = __expf(e0);
      denT += w0;
      bf16x8 r0 = *(const bf16x8*)&Wg[(size_t)s0 * F + cl * 8];
#pragma unroll
      for (int v = 0; v < VE; ++v) accT[v] += w0 * bf2f(r0[v]);
    }

#pragma unroll
    for (int o = 32; o >= LPR; o >>= 1) {
      denT += __shfl_xor(denT, o);
#pragma unroll
      for (int v = 0; v < VE; ++v) accT[v] += __shfl_xor(accT[v], o);
    }
    float rden = 1.f / denT;
#pragma unroll
    for (int v = 0; v < VE; ++v) acc[v] += accT[v] * rden;
  }

  if (g == 0) {
    if (OMODE == 0) {
#pragma unroll
      for (int q = 0; q < VE; q += 4) {
        float4 o4 = make_float4(acc[q], acc[q + 1], acc[q + 2], acc[q + 3]);
        *(float4*)&H[(size_t)d * F + cl * VE + q] = o4;
      }
    } else {
      bf16x8 hv, lv;
#pragma unroll
      for (int q = 0; q < VE; ++q) {
        float v = LRELU(acc[q]);
        bf16_t h = __float2bfloat16(v);
        bf16_t l = __float2bfloat16(v - __bfloat162float(h));
        short hb, lb;
        __builtin_memcpy(&hb, &h, 2);
        __builtin_memcpy(&lb, &l, 2);
        hv[q] = hb;
        lv[q] = lb;
      }
      *(bf16x8*)&Hh[(size_t)d * F + cl * 8] = hv;
      *(bf16x8*)&Hl[(size_t)d * F + cl * 8] = lv;
    }
  }
}

// ---------------------------------------------------------------------------
// launch
// ---------------------------------------------------------------------------
extern "C" void kernel_launch(void* const* d_in, const int* in_sizes, int n_in,
                              void* d_out, int out_size, void* d_ws,
                              size_t ws_size, hipStream_t stream) {
  const float* x    = (const float*)d_in[0];
  const float* W1_0 = (const float*)d_in[1];
  const float* b1_0 = (const float*)d_in[2];
  const float* a1_0 = (const float*)d_in[3];
  const float* W1_1 = (const float*)d_in[4];
  const float* b1_1 = (const float*)d_in[5];
  const float* a1_1 = (const float*)d_in[6];
  const float* W2_0 = (const float*)d_in[7];
  const float* b2_0 = (const float*)d_in[8];
  const float* a2_0 = (const float*)d_in[9];
  const float* W2_1 = (const float*)d_in[10];
  const float* b2_1 = (const float*)d_in[11];
  const float* a2_1 = (const float*)d_in[12];
  const int* src0 = (const int*)d_in[13];
  const int* dst0 = (const int*)d_in[14];
  const int* src1 = (const int*)d_in[15];
  const int* dst1 = (const int*)d_in[16];
  float* out = (float*)d_out;

  const int N = NNODES, E = NEDGES;

  char* w = (char*)d_ws;
  auto alloc = [&](size_t bytes) -> char* {
    char* p = w;
    w += (bytes + 255) & ~(size_t)255;
    return p;
  };
  int* row_off = (int*)alloc(2 * (N + 1) * sizeof(int));
  int* deg     = (int*)alloc(2 * N * sizeof(int));
  u16* pos0    = (u16*)alloc((size_t)E * 2);
  u16* pos1    = (u16*)alloc((size_t)E * 2);
  u16* srt0    = (u16*)alloc((size_t)E * 2);
  u16* srt1    = (u16*)alloc((size_t)E * 2);
  bf16_t* xh   = (bf16_t*)alloc((size_t)N * 128 * 2);
  bf16_t* xl   = (bf16_t*)alloc((size_t)N * 128 * 2);
  bf16_t* Whb_0 = (bf16_t*)alloc((size_t)N * 128 * 2);
  bf16_t* Whb_1 = (bf16_t*)alloc((size_t)N * 128 * 2);
  bf16_t* h1h  = (bf16_t*)alloc((size_t)N * 128 * 2);
  bf16_t* h1l  = (bf16_t*)alloc((size_t)N * 128 * 2);
  bf16_t* w1h0 = (bf16_t*)alloc(128 * 128 * 2);
  bf16_t* w1l0 = (bf16_t*)alloc(128 * 128 * 2);
  bf16_t* w1h1 = (bf16_t*)alloc(128 * 128 * 2);
  bf16_t* w1l1 = (bf16_t*)alloc(128 * 128 * 2);
  bf16_t* w2h0 = (bf16_t*)alloc(64 * 128 * 2);
  bf16_t* w2l0 = (bf16_t*)alloc(64 * 128 * 2);
  bf16_t* w2h1 = (bf16_t*)alloc(64 * 128 * 2);
  bf16_t* w2l1 = (bf16_t*)alloc(64 * 128 * 2);
  bf16_t* Wh2b_0 = (bf16_t*)alloc((size_t)N * 64 * 2);
  bf16_t* Wh2b_1 = (bf16_t*)alloc((size_t)N * 64 * 2);
  float* alA   = (float*)alloc(N * sizeof(float));
  float* arA   = (float*)alloc(N * sizeof(float));
  float* alB   = (float*)alloc(N * sizeof(float));
  float* arB   = (float*)alloc(N * sizeof(float));
  (void)ws_size;

  hipMemsetAsync(deg, 0, 2 * N * sizeof(int), stream);

  // L1: histpos || splits
  int preg = 2 * HB + SBX + 2 * SBW1 + 2 * SBW2;
  k_pre<<<preg, 256, 0, stream>>>(dst0, dst1, deg, pos0, pos1, x, xh, xl,
                                  W1_0, w1h0, w1l0, W1_1, w1h1, w1l1, W2_0,
                                  w2h0, w2l0, W2_1, w2h1, w2l1);
  // L2: scan
  k_scan<<<2, 1024, 0, stream>>>(deg, row_off, N);
  // L3: gemm1 || scatter
  int midg = 2 * GB + 2 * HB;
  k_mid<<<midg, 256, 0, stream>>>(xh, xl, w1h0, w1l0, w1h1, w1l1, b1_0, b1_1,
                                  a1_0, a1_1, Whb_0, Whb_1, alA, arA, alB,
                                  arB, src0, dst0, src1, dst1, pos0, pos1,
                                  row_off, srt0, srt1);
  // L4: agg layer 1 (F=128, bf16 gather, lrelu+split-bf16 out)
  int ngrid4 = (N + 3) / 4;
  k_agg2<128, 1><<<ngrid4, 256, 0, stream>>>(
      row_off, srt0, srt1, alA, arA, alB, arB, Whb_0, Whb_1, nullptr, h1h,
      h1l, N);
  // L5: gemm2 (F=64)
  k_gemm64<<<dim3(GB, 2), 256, 0, stream>>>(h1h, h1l, w2h0, w2l0, w2h1, w2l1,
                                            b2_0, b2_1, a2_0, a2_1, Wh2b_0,
                                            Wh2b_1, alA, arA, alB, arB);
  // L6: agg layer 2 (F=64, bf16 gather, fp32 out)
  k_agg2<64, 0><<<ngrid4, 256, 0, stream>>>(
      row_off, srt0, srt1, alA, arA, alB, arB, Wh2b_0, Wh2b_1, out, nullptr,
      nullptr, N);
}